// Round 8
// baseline (358.360 us; speedup 1.0000x reference)
//
#include <hip/hip_runtime.h>
#include <math.h>

#define NB   4
#define NH   16
#define SLQ  1024
#define SLK  2048
#define DM   1024
#define HD   64

typedef __attribute__((ext_vector_type(8))) short s16x8;
typedef __attribute__((ext_vector_type(4))) short s16x4;
typedef __attribute__((ext_vector_type(4))) float f32x4;
typedef __attribute__((ext_vector_type(2))) unsigned int u32x2;
typedef unsigned short u16;
typedef unsigned int   u32;

#if defined(__has_builtin)
#if __has_builtin(__builtin_amdgcn_exp2f)
#define EXP2(x) __builtin_amdgcn_exp2f(x)
#else
#define EXP2(x) exp2f(x)
#endif
#else
#define EXP2(x) exp2f(x)
#endif

// log2(e)/8 : folded into Q so scores are base-2 and pre-scaled by 1/sqrt(64)
#define SCALEQ 0.18033688011116012f

__device__ inline u16 f2bf(float f) {
  u32 u = __float_as_uint(f);
  u32 r = u + 0x7fffu + ((u >> 16) & 1u);
  return (u16)(r >> 16);
}
__device__ inline float bf2f(u16 h) { return __uint_as_float(((u32)h) << 16); }

// pack 2 f32 -> 2 bf16 (RNE), lo = a, hi = b
__device__ __forceinline__ u32 cvtpk(float a, float b) {
  u32 r;
  asm("v_cvt_pk_bf16_f32 %0, %1, %2" : "=v"(r) : "v"(a), "v"(b));
  return r;
}

// async global->LDS, 16B per lane; LDS dest must be wave-uniform base.
__device__ __forceinline__ void gl16(const void* g, void* l) {
  __builtin_amdgcn_global_load_lds(
      (const __attribute__((address_space(1))) unsigned int*)g,
      (__attribute__((address_space(3))) unsigned int*)l, 16, 0, 0);
}

// ---------------------------------------------------------------------------
// f32 -> bf16 (plain), vectorized 8/thread, grid-stride.
// ---------------------------------------------------------------------------
__global__ __launch_bounds__(256) void cvt_bf16_k(
    const float* __restrict__ src, u16* __restrict__ dst, int n) {
  int stride = gridDim.x * blockDim.x * 8;
  for (int i = (blockIdx.x * blockDim.x + threadIdx.x) * 8; i < n; i += stride) {
    float4 a = *(const float4*)(src + i);
    float4 b = *(const float4*)(src + i + 4);
    s16x8 o;
    o[0] = (short)f2bf(a.x); o[1] = (short)f2bf(a.y);
    o[2] = (short)f2bf(a.z); o[3] = (short)f2bf(a.w);
    o[4] = (short)f2bf(b.x); o[5] = (short)f2bf(b.y);
    o[6] = (short)f2bf(b.z); o[7] = (short)f2bf(b.w);
    *(s16x8*)(dst + i) = o;
  }
}

// ---------------------------------------------------------------------------
// mask -> bitmask (1 bit per (q,key)); wave ballot, 64 keys per wave-iter.
// ---------------------------------------------------------------------------
__global__ __launch_bounds__(256) void maskbits_k(
    const int* __restrict__ mask, unsigned long long* __restrict__ bits, int nwords) {
  int gw   = (blockIdx.x * blockDim.x + threadIdx.x) >> 6;
  int lane = threadIdx.x & 63;
  int nw   = (gridDim.x * blockDim.x) >> 6;
  for (int w = gw; w < nwords; w += nw) {
    int m = mask[(size_t)w * 64 + lane];
    unsigned long long b = __ballot(m != 0);
    if (lane == 0) bits[w] = b;
  }
}

// ---------------------------------------------------------------------------
// W[1024][1024] f32 -> WT [n][k] bf16 (transposed, plain).
// ---------------------------------------------------------------------------
__global__ __launch_bounds__(256) void convT_k(
    const float* __restrict__ W, u16* __restrict__ T) {
  __shared__ float ts[64][68];
  const int t = threadIdx.x;
  const int r0 = blockIdx.y * 64, c0 = blockIdx.x * 64;
  const int rr = t >> 4, cc = t & 15;
#pragma unroll
  for (int p = 0; p < 4; ++p) {
    float4 v = *(const float4*)(W + (size_t)(r0 + rr + p*16) * DM + c0 + cc*4);
    *(float4*)&ts[rr + p*16][cc*4] = v;
  }
  __syncthreads();
  const int c = t >> 2, ch = t & 3;
  s16x8 h0, h1;
#pragma unroll
  for (int i = 0; i < 8; ++i) {
    h0[i] = (short)f2bf(ts[ch*16 + i][c]);
    h1[i] = (short)f2bf(ts[ch*16 + 8 + i][c]);
  }
  size_t base = (size_t)(c0 + c) * DM + r0 + ch*16;
  *(s16x8*)(T + base) = h0; *(s16x8*)(T + base + 8) = h1;
}

// ---------------------------------------------------------------------------
// bf16 MFMA GEMM: C[M,1024] = A[M,1024] @ W + bias.  A bf16 [M][1024],
// BT bf16 [n][k].  128x128 tile, BK=32, 4 waves (2x2), 4x4 frags/wave.
// Staging: global_load_lds dwordx4 (1KB/wave-op), LINEAR LDS [128][32].
// OUT_MODE: 0 = bf16 natural, value scaled by oscale;
//           1 = bf16 transposed vT [b][h][dv][SLK]; 2 = f32 natural.
// ---------------------------------------------------------------------------
template<int OUT_MODE>
__global__ __launch_bounds__(256) void gemm_bf16_k(
    const u16* __restrict__ Ab, const u16* __restrict__ BT,
    const float* __restrict__ bias, void* __restrict__ Out, float oscale) {
  __shared__ u16 Ah[128 * 32];
  __shared__ u16 Bh[128 * 32];
  const int t = threadIdx.x;
  const int m0 = blockIdx.y * 128, n0 = blockIdx.x * 128;
  const int wid = t >> 6, lane = t & 63, lg = lane >> 4, lm = lane & 15;
  const int wr = wid >> 1, wc = wid & 1;
  f32x4 acc[4][4];
#pragma unroll
  for (int i = 0; i < 4; ++i)
#pragma unroll
    for (int j = 0; j < 4; ++j) acc[i][j] = (f32x4)(0.0f);

  const int c0 = wid * 2, c1 = wid * 2 + 1;
  const int sr0 = c0 * 16 + (lane >> 2), sr1 = c1 * 16 + (lane >> 2);
  const int spc = (lane & 3) * 8;
  for (int k0 = 0; k0 < DM; k0 += 32) {
    gl16(Ab + (size_t)(m0 + sr0) * DM + k0 + spc, &Ah[c0 * 512]);
    gl16(Ab + (size_t)(m0 + sr1) * DM + k0 + spc, &Ah[c1 * 512]);
    gl16(BT + (size_t)(n0 + sr0) * DM + k0 + spc, &Bh[c0 * 512]);
    gl16(BT + (size_t)(n0 + sr1) * DM + k0 + spc, &Bh[c1 * 512]);
    __syncthreads();
    s16x8 ah[4], bh[4];
#pragma unroll
    for (int i = 0; i < 4; ++i) {
      ah[i] = *(const s16x8*)&Ah[(wr*64 + i*16 + lm) * 32 + lg*8];
      bh[i] = *(const s16x8*)&Bh[(wc*64 + i*16 + lm) * 32 + lg*8];
    }
#pragma unroll
    for (int i = 0; i < 4; ++i)
#pragma unroll
      for (int j = 0; j < 4; ++j)
        acc[i][j] = __builtin_amdgcn_mfma_f32_16x16x32_bf16(ah[i], bh[j], acc[i][j], 0, 0, 0);
    __syncthreads();
  }
#pragma unroll
  for (int i = 0; i < 4; ++i)
#pragma unroll
    for (int j = 0; j < 4; ++j) {
      const int colg = n0 + wc*64 + j*16 + lm;
      const int rowb = m0 + wr*64 + i*16 + lg*4;
      const float bcol = bias[colg];
      if constexpr (OUT_MODE == 2) {
        float* O = (float*)Out;
#pragma unroll
        for (int r = 0; r < 4; ++r)
          O[(size_t)(rowb + r) * DM + colg] = acc[i][j][r] + bcol;
      } else if constexpr (OUT_MODE == 0) {
        u16* O = (u16*)Out;
#pragma unroll
        for (int r = 0; r < 4; ++r)
          O[(size_t)(rowb + r) * DM + colg] = f2bf((acc[i][j][r] + bcol) * oscale);
      } else {  // vT transposed bf16
        u16* OT = (u16*)Out;
        const int bb = rowb >> 11, key = rowb & 2047;
        const int hh = colg >> 6, dv = colg & 63;
        s16x4 pk;
#pragma unroll
        for (int r = 0; r < 4; ++r) pk[r] = (short)f2bf(acc[i][j][r] + bcol);
        *(s16x4*)(OT + (((size_t)bb*NH + hh)*HD + dv)*SLK + key) = pk;
      }
    }
}

// ---------------------------------------------------------------------------
// Flash attention, MFMA, plain bf16. Block = (qt64, h, b), 4 waves.
// Q pre-scaled by log2(e)/8 -> scores are base-2; softmax uses exp2.
// K staged with row permutation rho(k) = (k&3)*16 + (k>>2), so fragment j of
// QK^T holds key 4*lm+j: per-thread keys are CONSECUTIVE -> one-shift mask
// test, cvt_pk+ds_write_b64 P-store (natural key columns in ps).
// Deferred-max (base-2 thr 8); per-lane l partials, one final reduction.
// m stored base-2 in ml (wmean consistent).
// ---------------------------------------------------------------------------
__global__ __launch_bounds__(256) void attn_mfma_k(
    const u16* __restrict__ qb, const u16* __restrict__ kb,
    const u16* __restrict__ vT, const u32* __restrict__ mbits,
    u16* __restrict__ wv, float* __restrict__ ml) {
  __shared__ u16 ks[64][72];
  __shared__ u16 vs[64][72];
  __shared__ u16 ps[4][16][72];
  const int qt = blockIdx.x, h = blockIdx.y, b = blockIdx.z;
  const int t = threadIdx.x, wid = t >> 6, lane = t & 63, lg = lane >> 4, lm = lane & 15;
  const int q0 = qt * 64, qw = q0 + wid * 16;
  const int shamt = 4 * (lm & 7);     // bit shift for 4 consecutive keys
  s16x8 qh[2];
#pragma unroll
  for (int s = 0; s < 2; ++s) {
    size_t off = ((size_t)(b*SLQ + qw + lm)) * DM + h*HD + s*32 + lg*8;
    qh[s] = *(const s16x8*)(qb + off);
  }
  f32x4 O[4];
#pragma unroll
  for (int j = 0; j < 4; ++j) O[j] = (f32x4)(0.0f);
  float m_r[4] = {-INFINITY, -INFINITY, -INFINITY, -INFINITY};
  float l_r[4] = {0.f, 0.f, 0.f, 0.f};   // per-lane partials (16 lanes/row)
  const int srow = t >> 2, sch = t & 3;
  const int krow = ((srow & 3) << 4) + (srow >> 2);  // permuted K row
  for (int j0 = 0; j0 < SLK; j0 += 64) {
    {
      size_t koff = ((size_t)(b*SLK + j0 + srow)) * DM + h*HD + sch*16;
      *(s16x8*)&ks[krow][sch*16]     = *(const s16x8*)(kb + koff);
      *(s16x8*)&ks[krow][sch*16 + 8] = *(const s16x8*)(kb + koff + 8);
      size_t voff = (((size_t)b*NH + h)*HD + srow)*SLK + j0 + sch*16;
      *(s16x8*)&vs[srow][sch*16]     = *(const s16x8*)(vT + voff);
      *(s16x8*)&vs[srow][sch*16 + 8] = *(const s16x8*)(vT + voff + 8);
    }
    __syncthreads();
    // QK^T: fragment j, lane lm -> key 4*lm+j (base-2 scores)
    f32x4 sc[4];
#pragma unroll
    for (int j = 0; j < 4; ++j) {
      s16x8 kh0 = *(const s16x8*)&ks[j*16 + lm][lg*8];
      s16x8 kh1 = *(const s16x8*)&ks[j*16 + lm][32 + lg*8];
      f32x4 c = (f32x4)(0.0f);
      c = __builtin_amdgcn_mfma_f32_16x16x32_bf16(qh[0], kh0, c, 0, 0, 0);
      c = __builtin_amdgcn_mfma_f32_16x16x32_bf16(qh[1], kh1, c, 0, 0, 0);
      sc[j] = c;
    }
    // mask + deferred-max softmax per q-row (reg r)
#pragma unroll
    for (int r = 0; r < 4; ++r) {
      size_t mrow = ((size_t)(b*SLQ + qw + lg*4 + r)) * (SLK/32) + (j0 >> 5);
      u32 w0 = mbits[mrow], w1 = mbits[mrow + 1];
      u32 x = ((lm & 8) ? w1 : w0) >> shamt;   // bits 0..3 = keys 4lm..4lm+3
      float sv[4];
#pragma unroll
      for (int j = 0; j < 4; ++j)
        sv[j] = ((x >> j) & 1u) ? sc[j][r] : -1e9f;
      float pmax = fmaxf(fmaxf(sv[0], sv[1]), fmaxf(sv[2], sv[3]));
      if (!__all(pmax <= m_r[r] + 8.0f)) {       // slow path: rare
        float mx = pmax;
#pragma unroll
        for (int off = 1; off < 16; off <<= 1) mx = fmaxf(mx, __shfl_xor(mx, off, 64));
        float mnew  = fmaxf(m_r[r], mx);
        float alpha = EXP2(m_r[r] - mnew);       // m=-inf -> 0
        m_r[r] = mnew;
        l_r[r] *= alpha;
#pragma unroll
        for (int j = 0; j < 4; ++j) O[j][r] *= alpha;
      }
      float p0 = EXP2(sv[0] - m_r[r]);
      float p1 = EXP2(sv[1] - m_r[r]);
      float p2 = EXP2(sv[2] - m_r[r]);
      float p3 = EXP2(sv[3] - m_r[r]);
      l_r[r] += (p0 + p1) + (p2 + p3);
      u32x2 pk; pk[0] = cvtpk(p0, p1); pk[1] = cvtpk(p2, p3);
      *(u32x2*)&ps[wid][lg*4 + r][4*lm] = pk;    // keys 4lm..4lm+3 (natural)
    }
    // PV
    {
      s16x8 pa0 = *(const s16x8*)&ps[wid][lm][lg*8];
      s16x8 pa1 = *(const s16x8*)&ps[wid][lm][32 + lg*8];
#pragma unroll
      for (int j = 0; j < 4; ++j) {
        s16x8 vb0 = *(const s16x8*)&vs[j*16 + lm][lg*8];
        s16x8 vb1 = *(const s16x8*)&vs[j*16 + lm][32 + lg*8];
        O[j] = __builtin_amdgcn_mfma_f32_16x16x32_bf16(pa0, vb0, O[j], 0, 0, 0);
        O[j] = __builtin_amdgcn_mfma_f32_16x16x32_bf16(pa1, vb1, O[j], 0, 0, 0);
      }
    }
    __syncthreads();
  }
  // final l reduction across the 16 lanes of each row (once)
#pragma unroll
  for (int r = 0; r < 4; ++r) {
#pragma unroll
    for (int off = 1; off < 16; off <<= 1) l_r[r] += __shfl_xor(l_r[r], off, 64);
  }
#pragma unroll
  for (int j = 0; j < 4; ++j)
#pragma unroll
    for (int r = 0; r < 4; ++r) {
      float v = O[j][r] / l_r[r];
      size_t row = (size_t)(b*SLQ + qw + lg*4 + r);
      wv[row*DM + h*HD + j*16 + lm] = f2bf(v);
    }
  if (lm == 0) {
#pragma unroll
    for (int r = 0; r < 4; ++r) {
      float* mp = ml + ((size_t)(b*NH + h)*SLQ + qw + lg*4 + r) * 2;
      mp[0] = m_r[r]; mp[1] = l_r[r];
    }
  }
}

// ---------------------------------------------------------------------------
// weight_mean: block = ONE (64q x 64k) tile; 2048 blocks; loop h in-block.
// Same permuted-K staging -> per-thread keys 4lm..4lm+3; exp2 base-2 with
// attn's stored (m,l); masked -> 0; float4 coalesced store.
// ---------------------------------------------------------------------------
__global__ __launch_bounds__(256) void wmean_mfma_k(
    const u16* __restrict__ qb, const u16* __restrict__ kb,
    const u32* __restrict__ mbits, const float* __restrict__ ml,
    float* __restrict__ out1) {
  __shared__ u16 ks[64][72];
  const int t = threadIdx.x, wid = t >> 6, lane = t & 63, lg = lane >> 4, lm = lane & 15;
  const int j0 = blockIdx.x * 64, q0 = blockIdx.y * 64, b = blockIdx.z;
  const int qw = q0 + wid * 16;
  const int shamt = 4 * (lm & 7);
  const int srow = t >> 2, sch = t & 3;
  const int krow = ((srow & 3) << 4) + (srow >> 2);
  f32x4 wm[4];
#pragma unroll
  for (int j = 0; j < 4; ++j) wm[j] = (f32x4)(0.0f);
  u32 xr[4];
#pragma unroll
  for (int r = 0; r < 4; ++r) {
    size_t mrow = ((size_t)(b*SLQ + qw + lg*4 + r)) * (SLK/32) + (j0 >> 5);
    u32 w0 = mbits[mrow], w1 = mbits[mrow + 1];
    xr[r] = ((lm & 8) ? w1 : w0) >> shamt;
  }
  for (int h = 0; h < NH; ++h) {
    __syncthreads();   // previous-h ks reads done
    {
      size_t koff = ((size_t)(b*SLK + j0 + srow)) * DM + h*HD + sch*16;
      *(s16x8*)&ks[krow][sch*16]     = *(const s16x8*)(kb + koff);
      *(s16x8*)&ks[krow][sch*16 + 8] = *(const s16x8*)(kb + koff + 8);
    }
    __syncthreads();
    s16x8 qh0, qh1;
    {
      size_t off = ((size_t)(b*SLQ + qw + lm)) * DM + h*HD + lg*8;
      qh0 = *(const s16x8*)(qb + off);
      qh1 = *(const s16x8*)(qb + off + 32);
    }
    float mr[4], li[4];
#pragma unroll
    for (int r = 0; r < 4; ++r) {
      const float* mp = ml + ((size_t)(b*NH + h)*SLQ + qw + lg*4 + r) * 2;
      mr[r] = mp[0]; li[r] = 1.0f / mp[1];
    }
#pragma unroll
    for (int j = 0; j < 4; ++j) {
      s16x8 kh0 = *(const s16x8*)&ks[j*16 + lm][lg*8];
      s16x8 kh1 = *(const s16x8*)&ks[j*16 + lm][32 + lg*8];
      f32x4 c = (f32x4)(0.0f);
      c = __builtin_amdgcn_mfma_f32_16x16x32_bf16(qh0, kh0, c, 0, 0, 0);
      c = __builtin_amdgcn_mfma_f32_16x16x32_bf16(qh1, kh1, c, 0, 0, 0);
#pragma unroll
      for (int r = 0; r < 4; ++r) {
        float wvv = ((xr[r] >> j) & 1u) ? EXP2(c[r] - mr[r]) * li[r] : 0.f;
        wm[j][r] += wvv;
      }
    }
  }
#pragma unroll
  for (int r = 0; r < 4; ++r) {
    float4 o = make_float4(wm[0][r], wm[1][r], wm[2][r], wm[3][r]);
    o.x *= (1.0f/NH); o.y *= (1.0f/NH); o.z *= (1.0f/NH); o.w *= (1.0f/NH);
    *(float4*)(out1 + ((size_t)b*SLQ + qw + lg*4 + r) * SLK + j0 + 4*lm) = o;
  }
}

// ---------------------------------------------------------------------------
extern "C" void kernel_launch(void* const* d_in, const int* in_sizes, int n_in,
                              void* d_out, int out_size, void* d_ws, size_t ws_size,
                              hipStream_t stream) {
  const float* mq    = (const float*)d_in[0];
  const float* reply = (const float*)d_in[1];
  const int*   maskp = (const int*)  d_in[2];
  const float* Wq = (const float*)d_in[3];
  const float* bq = (const float*)d_in[4];
  const float* Wk = (const float*)d_in[5];
  const float* bk = (const float*)d_in[6];
  const float* Wv = (const float*)d_in[7];
  const float* bv = (const float*)d_in[8];
  const float* Wo = (const float*)d_in[9];
  const float* bo = (const float*)d_in[10];

  float* out0 = (float*)d_out;
  float* out1 = out0 + (size_t)NB*SLQ*DM;

  // workspace carve -- total ~82 MB
  char* w = (char*)d_ws;
  auto carve = [&](size_t bytes) { char* p = w; w += bytes; return p; };
  u16* WqT = (u16*)carve((size_t)DM*DM*2);
  u16* WkT = (u16*)carve((size_t)DM*DM*2);
  u16* WvT = (u16*)carve((size_t)DM*DM*2);
  u16* WoT = (u16*)carve((size_t)DM*DM*2);
  u16* mqb = (u16*)carve((size_t)NB*SLQ*DM*2);
  u16* rpb = (u16*)carve((size_t)NB*SLK*DM*2);
  u16* qbf = (u16*)carve((size_t)NB*SLQ*DM*2);
  u16* kbf = (u16*)carve((size_t)NB*SLK*DM*2);
  u16* vT  = (u16*)carve((size_t)NB*SLK*DM*2);
  u16* wvb = (u16*)carve((size_t)NB*SLQ*DM*2);
  float* mlb = (float*)carve((size_t)NB*NH*SLQ*2*4);
  unsigned long long* mbits = (unsigned long long*)carve((size_t)NB*SLQ*SLK/8);

  cvt_bf16_k<<<512, 256, 0, stream>>>(mq,    mqb, NB*SLQ*DM);
  cvt_bf16_k<<<512, 256, 0, stream>>>(reply, rpb, NB*SLK*DM);
  maskbits_k<<<256, 256, 0, stream>>>(maskp, mbits, NB*SLQ*SLK/64);
  dim3 tg(16, 16);
  convT_k<<<tg, 256, 0, stream>>>(Wq, WqT);
  convT_k<<<tg, 256, 0, stream>>>(Wk, WkT);
  convT_k<<<tg, 256, 0, stream>>>(Wv, WvT);
  convT_k<<<tg, 256, 0, stream>>>(Wo, WoT);

  gemm_bf16_k<0><<<dim3(DM/128, (NB*SLQ)/128), 256, 0, stream>>>(mqb, WqT, bq, qbf, SCALEQ);
  gemm_bf16_k<0><<<dim3(DM/128, (NB*SLK)/128), 256, 0, stream>>>(rpb, WkT, bk, kbf, 1.0f);
  gemm_bf16_k<1><<<dim3(DM/128, (NB*SLK)/128), 256, 0, stream>>>(rpb, WvT, bv, vT, 1.0f);

  attn_mfma_k<<<dim3(SLQ/64, NH, NB), 256, 0, stream>>>(
      qbf, kbf, vT, (const u32*)mbits, wvb, mlb);

  wmean_mfma_k<<<dim3(SLK/64, SLQ/64, NB), 256, 0, stream>>>(
      qbf, kbf, (const u32*)mbits, mlb, out1);

  gemm_bf16_k<2><<<dim3(DM/128, (NB*SLQ)/128), 256, 0, stream>>>(wvb, WoT, bo, out0, 1.0f);
}

// Round 9
// 340.469 us; speedup vs baseline: 1.0525x; 1.0525x over previous
//
#include <hip/hip_runtime.h>
#include <math.h>

#define NB   4
#define NH   16
#define SLQ  1024
#define SLK  2048
#define DM   1024
#define HD   64

typedef __attribute__((ext_vector_type(8))) short s16x8;
typedef __attribute__((ext_vector_type(4))) short s16x4;
typedef __attribute__((ext_vector_type(4))) float f32x4;
typedef __attribute__((ext_vector_type(2))) unsigned int u32x2;
typedef unsigned short u16;
typedef unsigned int   u32;

#if defined(__has_builtin)
#if __has_builtin(__builtin_amdgcn_exp2f)
#define EXP2(x) __builtin_amdgcn_exp2f(x)
#else
#define EXP2(x) exp2f(x)
#endif
#else
#define EXP2(x) exp2f(x)
#endif

// log2(e)/8 : folded into Q so scores are base-2 and pre-scaled by 1/sqrt(64)
#define SCALEQ 0.18033688011116012f

__device__ inline u16 f2bf(float f) {
  u32 u = __float_as_uint(f);
  u32 r = u + 0x7fffu + ((u >> 16) & 1u);
  return (u16)(r >> 16);
}
__device__ inline float bf2f(u16 h) { return __uint_as_float(((u32)h) << 16); }

// pack 2 f32 -> 2 bf16 (RNE), lo = a, hi = b
__device__ __forceinline__ u32 cvtpk(float a, float b) {
  u32 r;
  asm("v_cvt_pk_bf16_f32 %0, %1, %2" : "=v"(r) : "v"(a), "v"(b));
  return r;
}

// async global->LDS, 16B per lane; LDS dest must be wave-uniform base.
__device__ __forceinline__ void gl16(const void* g, void* l) {
  __builtin_amdgcn_global_load_lds(
      (const __attribute__((address_space(1))) unsigned int*)g,
      (__attribute__((address_space(3))) unsigned int*)l, 16, 0, 0);
}

// ---------------------------------------------------------------------------
// f32 -> bf16 (plain), vectorized 8/thread, grid-stride.
// ---------------------------------------------------------------------------
__global__ __launch_bounds__(256) void cvt_bf16_k(
    const float* __restrict__ src, u16* __restrict__ dst, int n) {
  int stride = gridDim.x * blockDim.x * 8;
  for (int i = (blockIdx.x * blockDim.x + threadIdx.x) * 8; i < n; i += stride) {
    float4 a = *(const float4*)(src + i);
    float4 b = *(const float4*)(src + i + 4);
    s16x8 o;
    o[0] = (short)f2bf(a.x); o[1] = (short)f2bf(a.y);
    o[2] = (short)f2bf(a.z); o[3] = (short)f2bf(a.w);
    o[4] = (short)f2bf(b.x); o[5] = (short)f2bf(b.y);
    o[6] = (short)f2bf(b.z); o[7] = (short)f2bf(b.w);
    *(s16x8*)(dst + i) = o;
  }
}

// ---------------------------------------------------------------------------
// mask -> bitmask (1 bit per (q,key)); wave ballot, 64 keys per wave-iter.
// ---------------------------------------------------------------------------
__global__ __launch_bounds__(256) void maskbits_k(
    const int* __restrict__ mask, unsigned long long* __restrict__ bits, int nwords) {
  int gw   = (blockIdx.x * blockDim.x + threadIdx.x) >> 6;
  int lane = threadIdx.x & 63;
  int nw   = (gridDim.x * blockDim.x) >> 6;
  for (int w = gw; w < nwords; w += nw) {
    int m = mask[(size_t)w * 64 + lane];
    unsigned long long b = __ballot(m != 0);
    if (lane == 0) bits[w] = b;
  }
}

// ---------------------------------------------------------------------------
// W[1024][1024] f32 -> WT [n][k] bf16 (transposed, plain).
// ---------------------------------------------------------------------------
__global__ __launch_bounds__(256) void convT_k(
    const float* __restrict__ W, u16* __restrict__ T) {
  __shared__ float ts[64][68];
  const int t = threadIdx.x;
  const int r0 = blockIdx.y * 64, c0 = blockIdx.x * 64;
  const int rr = t >> 4, cc = t & 15;
#pragma unroll
  for (int p = 0; p < 4; ++p) {
    float4 v = *(const float4*)(W + (size_t)(r0 + rr + p*16) * DM + c0 + cc*4);
    *(float4*)&ts[rr + p*16][cc*4] = v;
  }
  __syncthreads();
  const int c = t >> 2, ch = t & 3;
  s16x8 h0, h1;
#pragma unroll
  for (int i = 0; i < 8; ++i) {
    h0[i] = (short)f2bf(ts[ch*16 + i][c]);
    h1[i] = (short)f2bf(ts[ch*16 + 8 + i][c]);
  }
  size_t base = (size_t)(c0 + c) * DM + r0 + ch*16;
  *(s16x8*)(T + base) = h0; *(s16x8*)(T + base + 8) = h1;
}

// ---------------------------------------------------------------------------
// bf16 MFMA GEMM: C[M,1024] = A[M,1024] @ W + bias.  A bf16 [M][1024],
// BT bf16 [n][k].  128x128 tile, BK=32, 4 waves (2x2), 4x4 frags/wave.
// Staging: global_load_lds dwordx4 (1KB/wave-op), LINEAR LDS [128][32].
// OUT_MODE: 0 = bf16 natural, value scaled by oscale;
//           1 = bf16 transposed vT [b][h][dv][SLK], KEY-PERMUTED within each
//               64-block: position 4*(k&15)+((k>>4)&3) holds key k (so attn's
//               packed P columns line up with V columns);
//           2 = f32 natural.
// ---------------------------------------------------------------------------
template<int OUT_MODE>
__global__ __launch_bounds__(256) void gemm_bf16_k(
    const u16* __restrict__ Ab, const u16* __restrict__ BT,
    const float* __restrict__ bias, void* __restrict__ Out, float oscale) {
  __shared__ u16 Ah[128 * 32];
  __shared__ u16 Bh[128 * 32];
  const int t = threadIdx.x;
  const int m0 = blockIdx.y * 128, n0 = blockIdx.x * 128;
  const int wid = t >> 6, lane = t & 63, lg = lane >> 4, lm = lane & 15;
  const int wr = wid >> 1, wc = wid & 1;
  f32x4 acc[4][4];
#pragma unroll
  for (int i = 0; i < 4; ++i)
#pragma unroll
    for (int j = 0; j < 4; ++j) acc[i][j] = (f32x4)(0.0f);

  const int c0 = wid * 2, c1 = wid * 2 + 1;
  const int sr0 = c0 * 16 + (lane >> 2), sr1 = c1 * 16 + (lane >> 2);
  const int spc = (lane & 3) * 8;
  for (int k0 = 0; k0 < DM; k0 += 32) {
    gl16(Ab + (size_t)(m0 + sr0) * DM + k0 + spc, &Ah[c0 * 512]);
    gl16(Ab + (size_t)(m0 + sr1) * DM + k0 + spc, &Ah[c1 * 512]);
    gl16(BT + (size_t)(n0 + sr0) * DM + k0 + spc, &Bh[c0 * 512]);
    gl16(BT + (size_t)(n0 + sr1) * DM + k0 + spc, &Bh[c1 * 512]);
    __syncthreads();
    s16x8 ah[4], bh[4];
#pragma unroll
    for (int i = 0; i < 4; ++i) {
      ah[i] = *(const s16x8*)&Ah[(wr*64 + i*16 + lm) * 32 + lg*8];
      bh[i] = *(const s16x8*)&Bh[(wc*64 + i*16 + lm) * 32 + lg*8];
    }
#pragma unroll
    for (int i = 0; i < 4; ++i)
#pragma unroll
      for (int j = 0; j < 4; ++j)
        acc[i][j] = __builtin_amdgcn_mfma_f32_16x16x32_bf16(ah[i], bh[j], acc[i][j], 0, 0, 0);
    __syncthreads();
  }
#pragma unroll
  for (int i = 0; i < 4; ++i)
#pragma unroll
    for (int j = 0; j < 4; ++j) {
      const int colg = n0 + wc*64 + j*16 + lm;
      const int rowb = m0 + wr*64 + i*16 + lg*4;
      const float bcol = bias[colg];
      if constexpr (OUT_MODE == 2) {
        float* O = (float*)Out;
#pragma unroll
        for (int r = 0; r < 4; ++r)
          O[(size_t)(rowb + r) * DM + colg] = acc[i][j][r] + bcol;
      } else if constexpr (OUT_MODE == 0) {
        u16* O = (u16*)Out;
#pragma unroll
        for (int r = 0; r < 4; ++r)
          O[(size_t)(rowb + r) * DM + colg] = f2bf((acc[i][j][r] + bcol) * oscale);
      } else {  // vT transposed bf16, key-permuted within 64-blocks
        u16* OT = (u16*)Out;
        const int bb = rowb >> 11, key = rowb & 2047;
        const int hh = colg >> 6, dv = colg & 63;
        const int kb6 = key & ~63;          // 64-block base
        const int jj  = (key >> 4) & 3;     // fragment index of this key
        const int lmm = key & 15;           // key = jj*16 + lmm (+r on lmm)
        u16* basep = OT + (((size_t)bb*NH + hh)*HD + dv)*SLK + kb6 + jj;
#pragma unroll
        for (int r = 0; r < 4; ++r)
          basep[4*(lmm + r)] = f2bf(acc[i][j][r] + bcol);
      }
    }
}

// ---------------------------------------------------------------------------
// Flash attention, MFMA, plain bf16. Block = (qt64, h, b), 4 waves.
// Q pre-scaled by log2(e)/8 -> base-2 scores, exp2 softmax.
// K staged NATURAL (conflict-free); thread's fragment j = key j*16+lm.
// P stored packed at ps cols 4*lm..4*lm+3 (cvt_pk + ds_write_b64); vs columns
// carry the same permuted key order (vT is key-permuted globally), so PV's
// k-dims match. Deferred-max (thr 8 base-2); per-lane l partials.
// ---------------------------------------------------------------------------
__global__ __launch_bounds__(256) void attn_mfma_k(
    const u16* __restrict__ qb, const u16* __restrict__ kb,
    const u16* __restrict__ vT, const u32* __restrict__ mbits,
    u16* __restrict__ wv, float* __restrict__ ml) {
  __shared__ u16 ks[64][72];
  __shared__ u16 vs[64][72];
  __shared__ u16 ps[4][16][72];
  const int qt = blockIdx.x, h = blockIdx.y, b = blockIdx.z;
  const int t = threadIdx.x, wid = t >> 6, lane = t & 63, lg = lane >> 4, lm = lane & 15;
  const int q0 = qt * 64, qw = q0 + wid * 16;
  s16x8 qh[2];
#pragma unroll
  for (int s = 0; s < 2; ++s) {
    size_t off = ((size_t)(b*SLQ + qw + lm)) * DM + h*HD + s*32 + lg*8;
    qh[s] = *(const s16x8*)(qb + off);
  }
  f32x4 O[4];
#pragma unroll
  for (int j = 0; j < 4; ++j) O[j] = (f32x4)(0.0f);
  float m_r[4] = {-INFINITY, -INFINITY, -INFINITY, -INFINITY};
  float l_r[4] = {0.f, 0.f, 0.f, 0.f};   // per-lane partials (16 lanes/row)
  const int srow = t >> 2, sch = t & 3;
  for (int j0 = 0; j0 < SLK; j0 += 64) {
    {
      size_t koff = ((size_t)(b*SLK + j0 + srow)) * DM + h*HD + sch*16;
      *(s16x8*)&ks[srow][sch*16]     = *(const s16x8*)(kb + koff);
      *(s16x8*)&ks[srow][sch*16 + 8] = *(const s16x8*)(kb + koff + 8);
      size_t voff = (((size_t)b*NH + h)*HD + srow)*SLK + j0 + sch*16;
      *(s16x8*)&vs[srow][sch*16]     = *(const s16x8*)(vT + voff);
      *(s16x8*)&vs[srow][sch*16 + 8] = *(const s16x8*)(vT + voff + 8);
    }
    __syncthreads();
    // QK^T: fragment j, lane lm -> key j*16+lm (base-2 scores)
    f32x4 sc[4];
#pragma unroll
    for (int j = 0; j < 4; ++j) {
      s16x8 kh0 = *(const s16x8*)&ks[j*16 + lm][lg*8];
      s16x8 kh1 = *(const s16x8*)&ks[j*16 + lm][32 + lg*8];
      f32x4 c = (f32x4)(0.0f);
      c = __builtin_amdgcn_mfma_f32_16x16x32_bf16(qh[0], kh0, c, 0, 0, 0);
      c = __builtin_amdgcn_mfma_f32_16x16x32_bf16(qh[1], kh1, c, 0, 0, 0);
      sc[j] = c;
    }
    // mask + deferred-max softmax per q-row (reg r)
#pragma unroll
    for (int r = 0; r < 4; ++r) {
      size_t mrow = ((size_t)(b*SLQ + qw + lg*4 + r)) * (SLK/32) + (j0 >> 5);
      u32 x0 = mbits[mrow] >> lm, x1 = mbits[mrow + 1] >> lm;
      float sv[4];
      sv[0] = (x0 & 1u)         ? sc[0][r] : -1e9f;   // key lm
      sv[1] = ((x0 >> 16) & 1u) ? sc[1][r] : -1e9f;   // key 16+lm
      sv[2] = (x1 & 1u)         ? sc[2][r] : -1e9f;   // key 32+lm
      sv[3] = ((x1 >> 16) & 1u) ? sc[3][r] : -1e9f;   // key 48+lm
      float pmax = fmaxf(fmaxf(sv[0], sv[1]), fmaxf(sv[2], sv[3]));
      if (!__all(pmax <= m_r[r] + 8.0f)) {       // slow path: rare
        float mx = pmax;
#pragma unroll
        for (int off = 1; off < 16; off <<= 1) mx = fmaxf(mx, __shfl_xor(mx, off, 64));
        float mnew  = fmaxf(m_r[r], mx);
        float alpha = EXP2(m_r[r] - mnew);       // m=-inf -> 0
        m_r[r] = mnew;
        l_r[r] *= alpha;
#pragma unroll
        for (int j = 0; j < 4; ++j) O[j][r] *= alpha;
      }
      float p0 = EXP2(sv[0] - m_r[r]);
      float p1 = EXP2(sv[1] - m_r[r]);
      float p2 = EXP2(sv[2] - m_r[r]);
      float p3 = EXP2(sv[3] - m_r[r]);
      l_r[r] += (p0 + p1) + (p2 + p3);
      // packed store: ps col 4*lm+j holds key j*16+lm (matches vT permute)
      u32x2 pk; pk[0] = cvtpk(p0, p1); pk[1] = cvtpk(p2, p3);
      *(u32x2*)&ps[wid][lg*4 + r][4*lm] = pk;
    }
    // PV (ps and vs columns share the permuted key order)
    {
      s16x8 pa0 = *(const s16x8*)&ps[wid][lm][lg*8];
      s16x8 pa1 = *(const s16x8*)&ps[wid][lm][32 + lg*8];
#pragma unroll
      for (int j = 0; j < 4; ++j) {
        s16x8 vb0 = *(const s16x8*)&vs[j*16 + lm][lg*8];
        s16x8 vb1 = *(const s16x8*)&vs[j*16 + lm][32 + lg*8];
        O[j] = __builtin_amdgcn_mfma_f32_16x16x32_bf16(pa0, vb0, O[j], 0, 0, 0);
        O[j] = __builtin_amdgcn_mfma_f32_16x16x32_bf16(pa1, vb1, O[j], 0, 0, 0);
      }
    }
    __syncthreads();
  }
  // final l reduction across the 16 lanes of each row (once)
#pragma unroll
  for (int r = 0; r < 4; ++r) {
#pragma unroll
    for (int off = 1; off < 16; off <<= 1) l_r[r] += __shfl_xor(l_r[r], off, 64);
  }
#pragma unroll
  for (int j = 0; j < 4; ++j)
#pragma unroll
    for (int r = 0; r < 4; ++r) {
      float v = O[j][r] / l_r[r];
      size_t row = (size_t)(b*SLQ + qw + lg*4 + r);
      wv[row*DM + h*HD + j*16 + lm] = f2bf(v);
    }
  if (lm == 0) {
#pragma unroll
    for (int r = 0; r < 4; ++r) {
      float* mp = ml + ((size_t)(b*NH + h)*SLQ + qw + lg*4 + r) * 2;
      mp[0] = m_r[r]; mp[1] = l_r[r];
    }
  }
}

// ---------------------------------------------------------------------------
// weight_mean: block = ONE (64q x 64k) tile; 2048 blocks; loop h in-block.
// Natural K staging; fragment j = key j*16+lm; exp2 base-2 with attn's
// stored (m,l); masked -> 0; scalar f32 stores (16-lane coalesced runs).
// ---------------------------------------------------------------------------
__global__ __launch_bounds__(256) void wmean_mfma_k(
    const u16* __restrict__ qb, const u16* __restrict__ kb,
    const u32* __restrict__ mbits, const float* __restrict__ ml,
    float* __restrict__ out1) {
  __shared__ u16 ks[64][72];
  const int t = threadIdx.x, wid = t >> 6, lane = t & 63, lg = lane >> 4, lm = lane & 15;
  const int j0 = blockIdx.x * 64, q0 = blockIdx.y * 64, b = blockIdx.z;
  const int qw = q0 + wid * 16;
  const int srow = t >> 2, sch = t & 3;
  f32x4 wm[4];
#pragma unroll
  for (int j = 0; j < 4; ++j) wm[j] = (f32x4)(0.0f);
  u32 x0r[4], x1r[4];
#pragma unroll
  for (int r = 0; r < 4; ++r) {
    size_t mrow = ((size_t)(b*SLQ + qw + lg*4 + r)) * (SLK/32) + (j0 >> 5);
    x0r[r] = mbits[mrow] >> lm; x1r[r] = mbits[mrow + 1] >> lm;
  }
  for (int h = 0; h < NH; ++h) {
    __syncthreads();   // previous-h ks reads done
    {
      size_t koff = ((size_t)(b*SLK + j0 + srow)) * DM + h*HD + sch*16;
      *(s16x8*)&ks[srow][sch*16]     = *(const s16x8*)(kb + koff);
      *(s16x8*)&ks[srow][sch*16 + 8] = *(const s16x8*)(kb + koff + 8);
    }
    __syncthreads();
    s16x8 qh0, qh1;
    {
      size_t off = ((size_t)(b*SLQ + qw + lm)) * DM + h*HD + lg*8;
      qh0 = *(const s16x8*)(qb + off);
      qh1 = *(const s16x8*)(qb + off + 32);
    }
    float mr[4], li[4];
#pragma unroll
    for (int r = 0; r < 4; ++r) {
      const float* mp = ml + ((size_t)(b*NH + h)*SLQ + qw + lg*4 + r) * 2;
      mr[r] = mp[0]; li[r] = 1.0f / mp[1];
    }
#pragma unroll
    for (int j = 0; j < 4; ++j) {
      s16x8 kh0 = *(const s16x8*)&ks[j*16 + lm][lg*8];
      s16x8 kh1 = *(const s16x8*)&ks[j*16 + lm][32 + lg*8];
      f32x4 c = (f32x4)(0.0f);
      c = __builtin_amdgcn_mfma_f32_16x16x32_bf16(qh0, kh0, c, 0, 0, 0);
      c = __builtin_amdgcn_mfma_f32_16x16x32_bf16(qh1, kh1, c, 0, 0, 0);
      u32 xb = (j & 1) ? 16u : 0u;
#pragma unroll
      for (int r = 0; r < 4; ++r) {
        u32 x = (j < 2) ? x0r[r] : x1r[r];
        float wvv = ((x >> xb) & 1u) ? EXP2(c[r] - mr[r]) * li[r] : 0.f;
        wm[j][r] += wvv;
      }
    }
  }
#pragma unroll
  for (int j = 0; j < 4; ++j)
#pragma unroll
    for (int r = 0; r < 4; ++r)
      out1[((size_t)b*SLQ + qw + lg*4 + r) * SLK + j0 + j*16 + lm]
          = wm[j][r] * (1.0f / NH);
}

// ---------------------------------------------------------------------------
extern "C" void kernel_launch(void* const* d_in, const int* in_sizes, int n_in,
                              void* d_out, int out_size, void* d_ws, size_t ws_size,
                              hipStream_t stream) {
  const float* mq    = (const float*)d_in[0];
  const float* reply = (const float*)d_in[1];
  const int*   maskp = (const int*)  d_in[2];
  const float* Wq = (const float*)d_in[3];
  const float* bq = (const float*)d_in[4];
  const float* Wk = (const float*)d_in[5];
  const float* bk = (const float*)d_in[6];
  const float* Wv = (const float*)d_in[7];
  const float* bv = (const float*)d_in[8];
  const float* Wo = (const float*)d_in[9];
  const float* bo = (const float*)d_in[10];

  float* out0 = (float*)d_out;
  float* out1 = out0 + (size_t)NB*SLQ*DM;

  // workspace carve -- total ~82 MB
  char* w = (char*)d_ws;
  auto carve = [&](size_t bytes) { char* p = w; w += bytes; return p; };
  u16* WqT = (u16*)carve((size_t)DM*DM*2);
  u16* WkT = (u16*)carve((size_t)DM*DM*2);
  u16* WvT = (u16*)carve((size_t)DM*DM*2);
  u16* WoT = (u16*)carve((size_t)DM*DM*2);
  u16* mqb = (u16*)carve((size_t)NB*SLQ*DM*2);
  u16* rpb = (u16*)carve((size_t)NB*SLK*DM*2);
  u16* qbf = (u16*)carve((size_t)NB*SLQ*DM*2);
  u16* kbf = (u16*)carve((size_t)NB*SLK*DM*2);
  u16* vT  = (u16*)carve((size_t)NB*SLK*DM*2);
  u16* wvb = (u16*)carve((size_t)NB*SLQ*DM*2);
  float* mlb = (float*)carve((size_t)NB*NH*SLQ*2*4);
  unsigned long long* mbits = (unsigned long long*)carve((size_t)NB*SLQ*SLK/8);

  cvt_bf16_k<<<512, 256, 0, stream>>>(mq,    mqb, NB*SLQ*DM);
  cvt_bf16_k<<<512, 256, 0, stream>>>(reply, rpb, NB*SLK*DM);
  maskbits_k<<<256, 256, 0, stream>>>(maskp, mbits, NB*SLQ*SLK/64);
  dim3 tg(16, 16);
  convT_k<<<tg, 256, 0, stream>>>(Wq, WqT);
  convT_k<<<tg, 256, 0, stream>>>(Wk, WkT);
  convT_k<<<tg, 256, 0, stream>>>(Wv, WvT);
  convT_k<<<tg, 256, 0, stream>>>(Wo, WoT);

  gemm_bf16_k<0><<<dim3(DM/128, (NB*SLQ)/128), 256, 0, stream>>>(mqb, WqT, bq, qbf, SCALEQ);
  gemm_bf16_k<0><<<dim3(DM/128, (NB*SLK)/128), 256, 0, stream>>>(rpb, WkT, bk, kbf, 1.0f);
  gemm_bf16_k<1><<<dim3(DM/128, (NB*SLK)/128), 256, 0, stream>>>(rpb, WvT, bv, vT, 1.0f);

  attn_mfma_k<<<dim3(SLQ/64, NH, NB), 256, 0, stream>>>(
      qbf, kbf, vT, (const u32*)mbits, wvb, mlb);

  wmean_mfma_k<<<dim3(SLK/64, SLQ/64, NB), 256, 0, stream>>>(
      qbf, kbf, (const u32*)mbits, mlb, out1);

  gemm_bf16_k<2><<<dim3(DM/128, (NB*SLQ)/128), 256, 0, stream>>>(wvb, WoT, bo, out0, 1.0f);
}

// Round 10
// 320.019 us; speedup vs baseline: 1.1198x; 1.0639x over previous
//
#include <hip/hip_runtime.h>
#include <math.h>

#define NB   4
#define NH   16
#define SLQ  1024
#define SLK  2048
#define DM   1024
#define HD   64

typedef __attribute__((ext_vector_type(8))) short s16x8;
typedef __attribute__((ext_vector_type(4))) short s16x4;
typedef __attribute__((ext_vector_type(4))) float f32x4;
typedef unsigned short u16;
typedef unsigned int   u32;

__device__ inline u16 f2bf(float f) {
  u32 u = __float_as_uint(f);
  u32 r = u + 0x7fffu + ((u >> 16) & 1u);
  return (u16)(r >> 16);
}
__device__ inline float bf2f(u16 h) { return __uint_as_float(((u32)h) << 16); }

// async global->LDS, 16B per lane; LDS dest must be wave-uniform base.
__device__ __forceinline__ void gl16(const void* g, void* l) {
  __builtin_amdgcn_global_load_lds(
      (const __attribute__((address_space(1))) unsigned int*)g,
      (__attribute__((address_space(3))) unsigned int*)l, 16, 0, 0);
}

// ---------------------------------------------------------------------------
// f32 -> bf16 (plain), vectorized 8/thread, grid-stride.
// ---------------------------------------------------------------------------
__global__ __launch_bounds__(256) void cvt_bf16_k(
    const float* __restrict__ src, u16* __restrict__ dst, int n) {
  int stride = gridDim.x * blockDim.x * 8;
  for (int i = (blockIdx.x * blockDim.x + threadIdx.x) * 8; i < n; i += stride) {
    float4 a = *(const float4*)(src + i);
    float4 b = *(const float4*)(src + i + 4);
    s16x8 o;
    o[0] = (short)f2bf(a.x); o[1] = (short)f2bf(a.y);
    o[2] = (short)f2bf(a.z); o[3] = (short)f2bf(a.w);
    o[4] = (short)f2bf(b.x); o[5] = (short)f2bf(b.y);
    o[6] = (short)f2bf(b.z); o[7] = (short)f2bf(b.w);
    *(s16x8*)(dst + i) = o;
  }
}

// ---------------------------------------------------------------------------
// mask -> bitmask (1 bit per (q,key)); wave ballot, 64 keys per wave-iter.
// ---------------------------------------------------------------------------
__global__ __launch_bounds__(256) void maskbits_k(
    const int* __restrict__ mask, unsigned long long* __restrict__ bits, int nwords) {
  int gw   = (blockIdx.x * blockDim.x + threadIdx.x) >> 6;
  int lane = threadIdx.x & 63;
  int nw   = (gridDim.x * blockDim.x) >> 6;
  for (int w = gw; w < nwords; w += nw) {
    int m = mask[(size_t)w * 64 + lane];
    unsigned long long b = __ballot(m != 0);
    if (lane == 0) bits[w] = b;
  }
}

// ---------------------------------------------------------------------------
// W[1024][1024] f32 -> WT [n][k] bf16 (transposed, plain).
// ---------------------------------------------------------------------------
__global__ __launch_bounds__(256) void convT_k(
    const float* __restrict__ W, u16* __restrict__ T) {
  __shared__ float ts[64][68];
  const int t = threadIdx.x;
  const int r0 = blockIdx.y * 64, c0 = blockIdx.x * 64;
  const int rr = t >> 4, cc = t & 15;
#pragma unroll
  for (int p = 0; p < 4; ++p) {
    float4 v = *(const float4*)(W + (size_t)(r0 + rr + p*16) * DM + c0 + cc*4);
    *(float4*)&ts[rr + p*16][cc*4] = v;
  }
  __syncthreads();
  const int c = t >> 2, ch = t & 3;
  s16x8 h0, h1;
#pragma unroll
  for (int i = 0; i < 8; ++i) {
    h0[i] = (short)f2bf(ts[ch*16 + i][c]);
    h1[i] = (short)f2bf(ts[ch*16 + 8 + i][c]);
  }
  size_t base = (size_t)(c0 + c) * DM + r0 + ch*16;
  *(s16x8*)(T + base) = h0; *(s16x8*)(T + base + 8) = h1;
}

// ---------------------------------------------------------------------------
// Grouped projection GEMM: one launch computes q = mqb@WqT+bq (natural),
// k = rpb@WkT+bk (natural), v = rpb@WvT+bv (transposed vT).
// 1280 blocks: [0,256) q-proj (8n x 32m); [256,1280) k/v INTERLEAVED in
// pairs (even=k, odd=v) sharing the same A-tile -> 2nd read is an L2 hit.
// Body: 128x128 tile, BK=32, gl16 staging, LINEAR LDS [128][32].
// ---------------------------------------------------------------------------
__global__ __launch_bounds__(256) void proj_gemm_k(
    const u16* __restrict__ mqb, const u16* __restrict__ rpb,
    const u16* __restrict__ WqT, const u16* __restrict__ WkT,
    const u16* __restrict__ WvT,
    const float* __restrict__ bq, const float* __restrict__ bk,
    const float* __restrict__ bv,
    u16* __restrict__ qbf, u16* __restrict__ kbf, u16* __restrict__ vTp) {
  const int gid = blockIdx.x;
  const u16* A; const u16* BT; const float* bias; u16* out;
  int mode, mt, nt;
  if (gid < 256) {
    A = mqb; BT = WqT; bias = bq; out = qbf; mode = 0;
    nt = gid & 7; mt = gid >> 3;                  // mt in [0,32)
  } else {
    const int g = gid - 256, pair = g >> 1;       // pair in [0,512)
    nt = pair & 7; mt = pair >> 3;                // mt in [0,64)
    if ((g & 1) == 0) { A = rpb; BT = WkT; bias = bk; out = kbf; mode = 0; }
    else              { A = rpb; BT = WvT; bias = bv; out = vTp; mode = 1; }
  }
  const int m0 = mt * 128, n0 = nt * 128;

  __shared__ u16 Ah[128 * 32];
  __shared__ u16 Bh[128 * 32];
  const int t = threadIdx.x;
  const int wid = t >> 6, lane = t & 63, lg = lane >> 4, lm = lane & 15;
  const int wr = wid >> 1, wc = wid & 1;
  f32x4 acc[4][4];
#pragma unroll
  for (int i = 0; i < 4; ++i)
#pragma unroll
    for (int j = 0; j < 4; ++j) acc[i][j] = (f32x4)(0.0f);

  const int c0 = wid * 2, c1 = wid * 2 + 1;
  const int sr0 = c0 * 16 + (lane >> 2), sr1 = c1 * 16 + (lane >> 2);
  const int spc = (lane & 3) * 8;
  for (int k0 = 0; k0 < DM; k0 += 32) {
    gl16(A  + (size_t)(m0 + sr0) * DM + k0 + spc, &Ah[c0 * 512]);
    gl16(A  + (size_t)(m0 + sr1) * DM + k0 + spc, &Ah[c1 * 512]);
    gl16(BT + (size_t)(n0 + sr0) * DM + k0 + spc, &Bh[c0 * 512]);
    gl16(BT + (size_t)(n0 + sr1) * DM + k0 + spc, &Bh[c1 * 512]);
    __syncthreads();
    s16x8 ah[4], bh[4];
#pragma unroll
    for (int i = 0; i < 4; ++i) {
      ah[i] = *(const s16x8*)&Ah[(wr*64 + i*16 + lm) * 32 + lg*8];
      bh[i] = *(const s16x8*)&Bh[(wc*64 + i*16 + lm) * 32 + lg*8];
    }
#pragma unroll
    for (int i = 0; i < 4; ++i)
#pragma unroll
      for (int j = 0; j < 4; ++j)
        acc[i][j] = __builtin_amdgcn_mfma_f32_16x16x32_bf16(ah[i], bh[j], acc[i][j], 0, 0, 0);
    __syncthreads();
  }
#pragma unroll
  for (int i = 0; i < 4; ++i)
#pragma unroll
    for (int j = 0; j < 4; ++j) {
      const int colg = n0 + wc*64 + j*16 + lm;
      const int rowb = m0 + wr*64 + i*16 + lg*4;
      const float bcol = bias[colg];
      if (mode == 0) {
#pragma unroll
        for (int r = 0; r < 4; ++r)
          out[(size_t)(rowb + r) * DM + colg] = f2bf(acc[i][j][r] + bcol);
      } else {  // vT transposed bf16
        const int bb = rowb >> 11, key = rowb & 2047;
        const int hh = colg >> 6, dv = colg & 63;
        s16x4 pk;
#pragma unroll
        for (int r = 0; r < 4; ++r) pk[r] = (short)f2bf(acc[i][j][r] + bcol);
        *(s16x4*)(out + (((size_t)bb*NH + hh)*HD + dv)*SLK + key) = pk;
      }
    }
}

// ---------------------------------------------------------------------------
// Output projection GEMM: f32 out. Same body as proj.
// ---------------------------------------------------------------------------
__global__ __launch_bounds__(256) void gemm_o_k(
    const u16* __restrict__ Ab, const u16* __restrict__ BT,
    const float* __restrict__ bias, float* __restrict__ Out) {
  __shared__ u16 Ah[128 * 32];
  __shared__ u16 Bh[128 * 32];
  const int t = threadIdx.x;
  const int m0 = blockIdx.y * 128, n0 = blockIdx.x * 128;
  const int wid = t >> 6, lane = t & 63, lg = lane >> 4, lm = lane & 15;
  const int wr = wid >> 1, wc = wid & 1;
  f32x4 acc[4][4];
#pragma unroll
  for (int i = 0; i < 4; ++i)
#pragma unroll
    for (int j = 0; j < 4; ++j) acc[i][j] = (f32x4)(0.0f);

  const int c0 = wid * 2, c1 = wid * 2 + 1;
  const int sr0 = c0 * 16 + (lane >> 2), sr1 = c1 * 16 + (lane >> 2);
  const int spc = (lane & 3) * 8;
  for (int k0 = 0; k0 < DM; k0 += 32) {
    gl16(Ab + (size_t)(m0 + sr0) * DM + k0 + spc, &Ah[c0 * 512]);
    gl16(Ab + (size_t)(m0 + sr1) * DM + k0 + spc, &Ah[c1 * 512]);
    gl16(BT + (size_t)(n0 + sr0) * DM + k0 + spc, &Bh[c0 * 512]);
    gl16(BT + (size_t)(n0 + sr1) * DM + k0 + spc, &Bh[c1 * 512]);
    __syncthreads();
    s16x8 ah[4], bh[4];
#pragma unroll
    for (int i = 0; i < 4; ++i) {
      ah[i] = *(const s16x8*)&Ah[(wr*64 + i*16 + lm) * 32 + lg*8];
      bh[i] = *(const s16x8*)&Bh[(wc*64 + i*16 + lm) * 32 + lg*8];
    }
#pragma unroll
    for (int i = 0; i < 4; ++i)
#pragma unroll
      for (int j = 0; j < 4; ++j)
        acc[i][j] = __builtin_amdgcn_mfma_f32_16x16x32_bf16(ah[i], bh[j], acc[i][j], 0, 0, 0);
    __syncthreads();
  }
#pragma unroll
  for (int i = 0; i < 4; ++i)
#pragma unroll
    for (int j = 0; j < 4; ++j) {
      const int colg = n0 + wc*64 + j*16 + lm;
      const int rowb = m0 + wr*64 + i*16 + lg*4;
      const float bcol = bias[colg];
#pragma unroll
      for (int r = 0; r < 4; ++r)
        Out[(size_t)(rowb + r) * DM + colg] = acc[i][j][r] + bcol;
    }
}

// ---------------------------------------------------------------------------
// Flash attention, MFMA, plain bf16. Block = (qt64, h, b), 4 waves.
// ROUND-7 build (measured 106.7us, VGPR 64): natural K staging, __expf,
// deferred-max (thr 8), per-lane l partials, scalar ps stores.
// ---------------------------------------------------------------------------
__global__ __launch_bounds__(256) void attn_mfma_k(
    const u16* __restrict__ qb, const u16* __restrict__ kb,
    const u16* __restrict__ vT, const u32* __restrict__ mbits,
    u16* __restrict__ wv, float* __restrict__ ml) {
  __shared__ u16 ks[64][72];
  __shared__ u16 vs[64][72];
  __shared__ u16 ps[4][16][72];
  const int qt = blockIdx.x, h = blockIdx.y, b = blockIdx.z;
  const int t = threadIdx.x, wid = t >> 6, lane = t & 63, lg = lane >> 4, lm = lane & 15;
  const int q0 = qt * 64, qw = q0 + wid * 16;
  s16x8 qh[2];
#pragma unroll
  for (int s = 0; s < 2; ++s) {
    size_t off = ((size_t)(b*SLQ + qw + lm)) * DM + h*HD + s*32 + lg*8;
    qh[s] = *(const s16x8*)(qb + off);
  }
  f32x4 O[4];
#pragma unroll
  for (int j = 0; j < 4; ++j) O[j] = (f32x4)(0.0f);
  float m_r[4] = {-INFINITY, -INFINITY, -INFINITY, -INFINITY};
  float l_r[4] = {0.f, 0.f, 0.f, 0.f};   // per-lane partials (16 lanes/row)
  const int srow = t >> 2, sch = t & 3;
  for (int j0 = 0; j0 < SLK; j0 += 64) {
    {
      size_t koff = ((size_t)(b*SLK + j0 + srow)) * DM + h*HD + sch*16;
      *(s16x8*)&ks[srow][sch*16]     = *(const s16x8*)(kb + koff);
      *(s16x8*)&ks[srow][sch*16 + 8] = *(const s16x8*)(kb + koff + 8);
      size_t voff = (((size_t)b*NH + h)*HD + srow)*SLK + j0 + sch*16;
      *(s16x8*)&vs[srow][sch*16]     = *(const s16x8*)(vT + voff);
      *(s16x8*)&vs[srow][sch*16 + 8] = *(const s16x8*)(vT + voff + 8);
    }
    __syncthreads();
    // QK^T
    f32x4 sc[4];
#pragma unroll
    for (int j = 0; j < 4; ++j) {
      s16x8 kh0 = *(const s16x8*)&ks[j*16 + lm][lg*8];
      s16x8 kh1 = *(const s16x8*)&ks[j*16 + lm][32 + lg*8];
      f32x4 c = (f32x4)(0.0f);
      c = __builtin_amdgcn_mfma_f32_16x16x32_bf16(qh[0], kh0, c, 0, 0, 0);
      c = __builtin_amdgcn_mfma_f32_16x16x32_bf16(qh[1], kh1, c, 0, 0, 0);
      sc[j] = c;
    }
    // mask + deferred-max softmax per q-row (reg r)
#pragma unroll
    for (int r = 0; r < 4; ++r) {
      size_t mrow = ((size_t)(b*SLQ + qw + lg*4 + r)) * (SLK/32) + (j0 >> 5);
      u32 w0 = mbits[mrow], w1 = mbits[mrow + 1];
      float sv[4];
#pragma unroll
      for (int j = 0; j < 4; ++j) {
        u32 w = (j < 2) ? w0 : w1;
        int bit = (w >> ((j*16 + lm) & 31)) & 1;
        sv[j] = bit ? sc[j][r] * 0.125f : -1e9f;
      }
      float pmax = fmaxf(fmaxf(sv[0], sv[1]), fmaxf(sv[2], sv[3]));
      if (!__all(pmax <= m_r[r] + 8.0f)) {       // slow path: rare
        float mx = pmax;
#pragma unroll
        for (int off = 1; off < 16; off <<= 1) mx = fmaxf(mx, __shfl_xor(mx, off, 64));
        float mnew  = fmaxf(m_r[r], mx);
        float alpha = __expf(m_r[r] - mnew);     // m=-inf -> alpha=0
        m_r[r] = mnew;
        l_r[r] *= alpha;
#pragma unroll
        for (int j = 0; j < 4; ++j) O[j][r] *= alpha;
      }
      float p0 = __expf(sv[0] - m_r[r]);
      float p1 = __expf(sv[1] - m_r[r]);
      float p2 = __expf(sv[2] - m_r[r]);
      float p3 = __expf(sv[3] - m_r[r]);
      l_r[r] += (p0 + p1) + (p2 + p3);
      ps[wid][lg*4 + r][0*16 + lm] = f2bf(p0);
      ps[wid][lg*4 + r][1*16 + lm] = f2bf(p1);
      ps[wid][lg*4 + r][2*16 + lm] = f2bf(p2);
      ps[wid][lg*4 + r][3*16 + lm] = f2bf(p3);
    }
    // PV
    {
      s16x8 pa0 = *(const s16x8*)&ps[wid][lm][lg*8];
      s16x8 pa1 = *(const s16x8*)&ps[wid][lm][32 + lg*8];
#pragma unroll
      for (int j = 0; j < 4; ++j) {
        s16x8 vb0 = *(const s16x8*)&vs[j*16 + lm][lg*8];
        s16x8 vb1 = *(const s16x8*)&vs[j*16 + lm][32 + lg*8];
        O[j] = __builtin_amdgcn_mfma_f32_16x16x32_bf16(pa0, vb0, O[j], 0, 0, 0);
        O[j] = __builtin_amdgcn_mfma_f32_16x16x32_bf16(pa1, vb1, O[j], 0, 0, 0);
      }
    }
    __syncthreads();
  }
  // final l reduction across the 16 lanes of each row (once)
#pragma unroll
  for (int r = 0; r < 4; ++r) {
#pragma unroll
    for (int off = 1; off < 16; off <<= 1) l_r[r] += __shfl_xor(l_r[r], off, 64);
  }
#pragma unroll
  for (int j = 0; j < 4; ++j)
#pragma unroll
    for (int r = 0; r < 4; ++r) {
      float v = O[j][r] / l_r[r];
      size_t row = (size_t)(b*SLQ + qw + lg*4 + r);
      wv[row*DM + h*HD + j*16 + lm] = f2bf(v);
    }
  if (lm == 0) {
#pragma unroll
    for (int r = 0; r < 4; ++r) {
      float* mp = ml + ((size_t)(b*NH + h)*SLQ + qw + lg*4 + r) * 2;
      mp[0] = m_r[r]; mp[1] = l_r[r];
    }
  }
}

// ---------------------------------------------------------------------------
// weight_mean: block = ONE (64q x 64k) tile; 2048 blocks; loop h in-block.
// ROUND-7 build: natural K staging, __expf, attn's stored (m,l).
// ---------------------------------------------------------------------------
__global__ __launch_bounds__(256) void wmean_mfma_k(
    const u16* __restrict__ qb, const u16* __restrict__ kb,
    const u32* __restrict__ mbits, const float* __restrict__ ml,
    float* __restrict__ out1) {
  __shared__ u16 ks[64][72];
  const int t = threadIdx.x, wid = t >> 6, lane = t & 63, lg = lane >> 4, lm = lane & 15;
  const int j0 = blockIdx.x * 64, q0 = blockIdx.y * 64, b = blockIdx.z;
  const int qw = q0 + wid * 16;
  const int srow = t >> 2, sch = t & 3;
  f32x4 wm[4];
#pragma unroll
  for (int j = 0; j < 4; ++j) wm[j] = (f32x4)(0.0f);
  u32 w0[4], w1[4];
#pragma unroll
  for (int r = 0; r < 4; ++r) {
    size_t mrow = ((size_t)(b*SLQ + qw + lg*4 + r)) * (SLK/32) + (j0 >> 5);
    w0[r] = mbits[mrow]; w1[r] = mbits[mrow + 1];
  }
  for (int h = 0; h < NH; ++h) {
    __syncthreads();   // previous-h ks reads done
    {
      size_t koff = ((size_t)(b*SLK + j0 + srow)) * DM + h*HD + sch*16;
      *(s16x8*)&ks[srow][sch*16]     = *(const s16x8*)(kb + koff);
      *(s16x8*)&ks[srow][sch*16 + 8] = *(const s16x8*)(kb + koff + 8);
    }
    __syncthreads();
    s16x8 qh0, qh1;
    {
      size_t off = ((size_t)(b*SLQ + qw + lm)) * DM + h*HD + lg*8;
      qh0 = *(const s16x8*)(qb + off);
      qh1 = *(const s16x8*)(qb + off + 32);
    }
    float mr[4], li[4];
#pragma unroll
    for (int r = 0; r < 4; ++r) {
      const float* mp = ml + ((size_t)(b*NH + h)*SLQ + qw + lg*4 + r) * 2;
      mr[r] = mp[0]; li[r] = 1.0f / mp[1];
    }
#pragma unroll
    for (int j = 0; j < 4; ++j) {
      s16x8 kh0 = *(const s16x8*)&ks[j*16 + lm][lg*8];
      s16x8 kh1 = *(const s16x8*)&ks[j*16 + lm][32 + lg*8];
      f32x4 c = (f32x4)(0.0f);
      c = __builtin_amdgcn_mfma_f32_16x16x32_bf16(qh0, kh0, c, 0, 0, 0);
      c = __builtin_amdgcn_mfma_f32_16x16x32_bf16(qh1, kh1, c, 0, 0, 0);
#pragma unroll
      for (int r = 0; r < 4; ++r) {
        u32 w = (j < 2) ? w0[r] : w1[r];
        int bit = (w >> ((j*16 + lm) & 31)) & 1;
        float wvv = bit ? __expf(c[r] * 0.125f - mr[r]) * li[r] : 0.f;
        wm[j][r] += wvv;
      }
    }
  }
#pragma unroll
  for (int j = 0; j < 4; ++j)
#pragma unroll
    for (int r = 0; r < 4; ++r)
      out1[((size_t)b*SLQ + qw + lg*4 + r) * SLK + j0 + j*16 + lm]
          = wm[j][r] * (1.0f / NH);
}

// ---------------------------------------------------------------------------
extern "C" void kernel_launch(void* const* d_in, const int* in_sizes, int n_in,
                              void* d_out, int out_size, void* d_ws, size_t ws_size,
                              hipStream_t stream) {
  const float* mq    = (const float*)d_in[0];
  const float* reply = (const float*)d_in[1];
  const int*   maskp = (const int*)  d_in[2];
  const float* Wq = (const float*)d_in[3];
  const float* bq = (const float*)d_in[4];
  const float* Wk = (const float*)d_in[5];
  const float* bk = (const float*)d_in[6];
  const float* Wv = (const float*)d_in[7];
  const float* bv = (const float*)d_in[8];
  const float* Wo = (const float*)d_in[9];
  const float* bo = (const float*)d_in[10];

  float* out0 = (float*)d_out;
  float* out1 = out0 + (size_t)NB*SLQ*DM;

  // workspace carve -- total ~82 MB
  char* w = (char*)d_ws;
  auto carve = [&](size_t bytes) { char* p = w; w += bytes; return p; };
  u16* WqT = (u16*)carve((size_t)DM*DM*2);
  u16* WkT = (u16*)carve((size_t)DM*DM*2);
  u16* WvT = (u16*)carve((size_t)DM*DM*2);
  u16* WoT = (u16*)carve((size_t)DM*DM*2);
  u16* mqb = (u16*)carve((size_t)NB*SLQ*DM*2);
  u16* rpb = (u16*)carve((size_t)NB*SLK*DM*2);
  u16* qbf = (u16*)carve((size_t)NB*SLQ*DM*2);
  u16* kbf = (u16*)carve((size_t)NB*SLK*DM*2);
  u16* vT  = (u16*)carve((size_t)NB*SLK*DM*2);
  u16* wvb = (u16*)carve((size_t)NB*SLQ*DM*2);
  float* mlb = (float*)carve((size_t)NB*NH*SLQ*2*4);
  unsigned long long* mbits = (unsigned long long*)carve((size_t)NB*SLQ*SLK/8);

  cvt_bf16_k<<<512, 256, 0, stream>>>(mq,    mqb, NB*SLQ*DM);
  cvt_bf16_k<<<512, 256, 0, stream>>>(reply, rpb, NB*SLK*DM);
  maskbits_k<<<256, 256, 0, stream>>>(maskp, mbits, NB*SLQ*SLK/64);
  dim3 tg(16, 16);
  convT_k<<<tg, 256, 0, stream>>>(Wq, WqT);
  convT_k<<<tg, 256, 0, stream>>>(Wk, WkT);
  convT_k<<<tg, 256, 0, stream>>>(Wv, WvT);
  convT_k<<<tg, 256, 0, stream>>>(Wo, WoT);

  // grouped q/k/v projections: one 1280-block launch
  proj_gemm_k<<<1280, 256, 0, stream>>>(
      mqb, rpb, WqT, WkT, WvT, bq, bk, bv, qbf, kbf, vT);

  attn_mfma_k<<<dim3(SLQ/64, NH, NB), 256, 0, stream>>>(
      qbf, kbf, vT, (const u32*)mbits, wvb, mlb);

  wmean_mfma_k<<<dim3(SLK/64, SLQ/64, NB), 256, 0, stream>>>(
      qbf, kbf, (const u32*)mbits, mlb, out1);

  gemm_o_k<<<dim3(DM/128, (NB*SLQ)/128), 256, 0, stream>>>(wvb, WoT, bo, out0);
}

// Round 11
// 307.102 us; speedup vs baseline: 1.1669x; 1.0421x over previous
//
#include <hip/hip_runtime.h>
#include <math.h>

#define NB   4
#define NH   16
#define SLQ  1024
#define SLK  2048
#define DM   1024
#define HD   64

typedef __attribute__((ext_vector_type(8))) short s16x8;
typedef __attribute__((ext_vector_type(4))) short s16x4;
typedef __attribute__((ext_vector_type(4))) float f32x4;
typedef unsigned short u16;
typedef unsigned int   u32;

#if defined(__has_builtin)
#if __has_builtin(__builtin_amdgcn_exp2f)
#define EXP2(x) __builtin_amdgcn_exp2f(x)
#else
#define EXP2(x) exp2f(x)
#endif
#else
#define EXP2(x) exp2f(x)
#endif

// 0.125 * log2(e): scores scaled to base-2 inside attn/wmean
#define C2 0.18033688011116012f

__device__ inline u16 f2bf(float f) {
  u32 u = __float_as_uint(f);
  u32 r = u + 0x7fffu + ((u >> 16) & 1u);
  return (u16)(r >> 16);
}
__device__ inline float bf2f(u16 h) { return __uint_as_float(((u32)h) << 16); }

// pack 2 f32 -> 2 bf16 (RNE), lo = a, hi = b
__device__ __forceinline__ u32 cvtpk(float a, float b) {
  u32 r;
  asm("v_cvt_pk_bf16_f32 %0, %1, %2" : "=v"(r) : "v"(a), "v"(b));
  return r;
}

// async global->LDS, 16B per lane; LDS dest must be wave-uniform base.
__device__ __forceinline__ void gl16(const void* g, void* l) {
  __builtin_amdgcn_global_load_lds(
      (const __attribute__((address_space(1))) unsigned int*)g,
      (__attribute__((address_space(3))) unsigned int*)l, 16, 0, 0);
}

// ---------------------------------------------------------------------------
// f32 -> bf16 for BOTH inputs in one launch, vectorized 8/thread, grid-stride.
// ---------------------------------------------------------------------------
__global__ __launch_bounds__(256) void cvt2_bf16_k(
    const float* __restrict__ a, u16* __restrict__ da, int na,
    const float* __restrict__ b, u16* __restrict__ db, int nb) {
  int stride = gridDim.x * blockDim.x * 8;
  for (int i = (blockIdx.x * blockDim.x + threadIdx.x) * 8; i < na + nb; i += stride) {
    const float* s; u16* d; int off;
    if (i < na) { s = a; d = da; off = i; } else { s = b; d = db; off = i - na; }
    float4 x = *(const float4*)(s + off);
    float4 y = *(const float4*)(s + off + 4);
    s16x8 o;
    o[0] = (short)f2bf(x.x); o[1] = (short)f2bf(x.y);
    o[2] = (short)f2bf(x.z); o[3] = (short)f2bf(x.w);
    o[4] = (short)f2bf(y.x); o[5] = (short)f2bf(y.y);
    o[6] = (short)f2bf(y.z); o[7] = (short)f2bf(y.w);
    *(s16x8*)(d + off) = o;
  }
}

// ---------------------------------------------------------------------------
// mask -> bitmask (1 bit per (q,key)); wave ballot, 64 keys per wave-iter.
// ---------------------------------------------------------------------------
__global__ __launch_bounds__(256) void maskbits_k(
    const int* __restrict__ mask, unsigned long long* __restrict__ bits, int nwords) {
  int gw   = (blockIdx.x * blockDim.x + threadIdx.x) >> 6;
  int lane = threadIdx.x & 63;
  int nw   = (gridDim.x * blockDim.x) >> 6;
  for (int w = gw; w < nwords; w += nw) {
    int m = mask[(size_t)w * 64 + lane];
    unsigned long long b = __ballot(m != 0);
    if (lane == 0) bits[w] = b;
  }
}

// ---------------------------------------------------------------------------
// All four W[1024][1024] f32 -> WT [n][k] bf16 in one launch (grid.z picks W).
// ---------------------------------------------------------------------------
__global__ __launch_bounds__(256) void convT4_k(
    const float* __restrict__ W0, const float* __restrict__ W1,
    const float* __restrict__ W2, const float* __restrict__ W3,
    u16* __restrict__ T0, u16* __restrict__ T1,
    u16* __restrict__ T2, u16* __restrict__ T3) {
  const float* W; u16* T;
  switch (blockIdx.z) {
    case 0:  W = W0; T = T0; break;
    case 1:  W = W1; T = T1; break;
    case 2:  W = W2; T = T2; break;
    default: W = W3; T = T3; break;
  }
  __shared__ float ts[64][68];
  const int t = threadIdx.x;
  const int r0 = blockIdx.y * 64, c0 = blockIdx.x * 64;
  const int rr = t >> 4, cc = t & 15;
#pragma unroll
  for (int p = 0; p < 4; ++p) {
    float4 v = *(const float4*)(W + (size_t)(r0 + rr + p*16) * DM + c0 + cc*4);
    *(float4*)&ts[rr + p*16][cc*4] = v;
  }
  __syncthreads();
  const int c = t >> 2, ch = t & 3;
  s16x8 h0, h1;
#pragma unroll
  for (int i = 0; i < 8; ++i) {
    h0[i] = (short)f2bf(ts[ch*16 + i][c]);
    h1[i] = (short)f2bf(ts[ch*16 + 8 + i][c]);
  }
  size_t base = (size_t)(c0 + c) * DM + r0 + ch*16;
  *(s16x8*)(T + base) = h0; *(s16x8*)(T + base + 8) = h1;
}

// ---------------------------------------------------------------------------
// Grouped projection GEMM: one launch computes q = mqb@WqT+bq (natural),
// k = rpb@WkT+bk (natural), v = rpb@WvT+bv (transposed vT).
// 1280 blocks: [0,256) q-proj; [256,1280) k/v interleaved in pairs sharing
// the same A-tile (2nd read is an L2 hit). 128x128 tile, BK=32, gl16.
// ---------------------------------------------------------------------------
__global__ __launch_bounds__(256) void proj_gemm_k(
    const u16* __restrict__ mqb, const u16* __restrict__ rpb,
    const u16* __restrict__ WqT, const u16* __restrict__ WkT,
    const u16* __restrict__ WvT,
    const float* __restrict__ bq, const float* __restrict__ bk,
    const float* __restrict__ bv,
    u16* __restrict__ qbf, u16* __restrict__ kbf, u16* __restrict__ vTp) {
  const int gid = blockIdx.x;
  const u16* A; const u16* BT; const float* bias; u16* out;
  int mode, mt, nt;
  if (gid < 256) {
    A = mqb; BT = WqT; bias = bq; out = qbf; mode = 0;
    nt = gid & 7; mt = gid >> 3;
  } else {
    const int g = gid - 256, pair = g >> 1;
    nt = pair & 7; mt = pair >> 3;
    if ((g & 1) == 0) { A = rpb; BT = WkT; bias = bk; out = kbf; mode = 0; }
    else              { A = rpb; BT = WvT; bias = bv; out = vTp; mode = 1; }
  }
  const int m0 = mt * 128, n0 = nt * 128;

  __shared__ u16 Ah[128 * 32];
  __shared__ u16 Bh[128 * 32];
  const int t = threadIdx.x;
  const int wid = t >> 6, lane = t & 63, lg = lane >> 4, lm = lane & 15;
  const int wr = wid >> 1, wc = wid & 1;
  f32x4 acc[4][4];
#pragma unroll
  for (int i = 0; i < 4; ++i)
#pragma unroll
    for (int j = 0; j < 4; ++j) acc[i][j] = (f32x4)(0.0f);

  const int c0 = wid * 2, c1 = wid * 2 + 1;
  const int sr0 = c0 * 16 + (lane >> 2), sr1 = c1 * 16 + (lane >> 2);
  const int spc = (lane & 3) * 8;
  for (int k0 = 0; k0 < DM; k0 += 32) {
    gl16(A  + (size_t)(m0 + sr0) * DM + k0 + spc, &Ah[c0 * 512]);
    gl16(A  + (size_t)(m0 + sr1) * DM + k0 + spc, &Ah[c1 * 512]);
    gl16(BT + (size_t)(n0 + sr0) * DM + k0 + spc, &Bh[c0 * 512]);
    gl16(BT + (size_t)(n0 + sr1) * DM + k0 + spc, &Bh[c1 * 512]);
    __syncthreads();
    s16x8 ah[4], bh[4];
#pragma unroll
    for (int i = 0; i < 4; ++i) {
      ah[i] = *(const s16x8*)&Ah[(wr*64 + i*16 + lm) * 32 + lg*8];
      bh[i] = *(const s16x8*)&Bh[(wc*64 + i*16 + lm) * 32 + lg*8];
    }
#pragma unroll
    for (int i = 0; i < 4; ++i)
#pragma unroll
      for (int j = 0; j < 4; ++j)
        acc[i][j] = __builtin_amdgcn_mfma_f32_16x16x32_bf16(ah[i], bh[j], acc[i][j], 0, 0, 0);
    __syncthreads();
  }
#pragma unroll
  for (int i = 0; i < 4; ++i)
#pragma unroll
    for (int j = 0; j < 4; ++j) {
      const int colg = n0 + wc*64 + j*16 + lm;
      const int rowb = m0 + wr*64 + i*16 + lg*4;
      const float bcol = bias[colg];
      if (mode == 0) {
#pragma unroll
        for (int r = 0; r < 4; ++r)
          out[(size_t)(rowb + r) * DM + colg] = f2bf(acc[i][j][r] + bcol);
      } else {  // vT transposed bf16
        const int bb = rowb >> 11, key = rowb & 2047;
        const int hh = colg >> 6, dv = colg & 63;
        s16x4 pk;
#pragma unroll
        for (int r = 0; r < 4; ++r) pk[r] = (short)f2bf(acc[i][j][r] + bcol);
        *(s16x4*)(out + (((size_t)bb*NH + hh)*HD + dv)*SLK + key) = pk;
      }
    }
}

// ---------------------------------------------------------------------------
// Output projection GEMM: f32 out. Same body as proj.
// ---------------------------------------------------------------------------
__global__ __launch_bounds__(256) void gemm_o_k(
    const u16* __restrict__ Ab, const u16* __restrict__ BT,
    const float* __restrict__ bias, float* __restrict__ Out) {
  __shared__ u16 Ah[128 * 32];
  __shared__ u16 Bh[128 * 32];
  const int t = threadIdx.x;
  const int m0 = blockIdx.y * 128, n0 = blockIdx.x * 128;
  const int wid = t >> 6, lane = t & 63, lg = lane >> 4, lm = lane & 15;
  const int wr = wid >> 1, wc = wid & 1;
  f32x4 acc[4][4];
#pragma unroll
  for (int i = 0; i < 4; ++i)
#pragma unroll
    for (int j = 0; j < 4; ++j) acc[i][j] = (f32x4)(0.0f);

  const int c0 = wid * 2, c1 = wid * 2 + 1;
  const int sr0 = c0 * 16 + (lane >> 2), sr1 = c1 * 16 + (lane >> 2);
  const int spc = (lane & 3) * 8;
  for (int k0 = 0; k0 < DM; k0 += 32) {
    gl16(Ab + (size_t)(m0 + sr0) * DM + k0 + spc, &Ah[c0 * 512]);
    gl16(Ab + (size_t)(m0 + sr1) * DM + k0 + spc, &Ah[c1 * 512]);
    gl16(BT + (size_t)(n0 + sr0) * DM + k0 + spc, &Bh[c0 * 512]);
    gl16(BT + (size_t)(n0 + sr1) * DM + k0 + spc, &Bh[c1 * 512]);
    __syncthreads();
    s16x8 ah[4], bh[4];
#pragma unroll
    for (int i = 0; i < 4; ++i) {
      ah[i] = *(const s16x8*)&Ah[(wr*64 + i*16 + lm) * 32 + lg*8];
      bh[i] = *(const s16x8*)&Bh[(wc*64 + i*16 + lm) * 32 + lg*8];
    }
#pragma unroll
    for (int i = 0; i < 4; ++i)
#pragma unroll
      for (int j = 0; j < 4; ++j)
        acc[i][j] = __builtin_amdgcn_mfma_f32_16x16x32_bf16(ah[i], bh[j], acc[i][j], 0, 0, 0);
    __syncthreads();
  }
#pragma unroll
  for (int i = 0; i < 4; ++i)
#pragma unroll
    for (int j = 0; j < 4; ++j) {
      const int colg = n0 + wc*64 + j*16 + lm;
      const int rowb = m0 + wr*64 + i*16 + lg*4;
      const float bcol = bias[colg];
#pragma unroll
      for (int r = 0; r < 4; ++r)
        Out[(size_t)(rowb + r) * DM + colg] = acc[i][j][r] + bcol;
    }
}

// ---------------------------------------------------------------------------
// Flash attention, MFMA, plain bf16. Block = (qt64, h, b), 4 waves.
// Round-7 structure (VGPR 64) with two register-neutral VALU cuts:
// base-2 softmax (sv = sc*C2 -> exp2; m,l stored base-2) and cvt_pk P-pair
// conversion (same ps addresses, 4x ds_write_b16).
// ---------------------------------------------------------------------------
__global__ __launch_bounds__(256) void attn_mfma_k(
    const u16* __restrict__ qb, const u16* __restrict__ kb,
    const u16* __restrict__ vT, const u32* __restrict__ mbits,
    u16* __restrict__ wv, float* __restrict__ ml) {
  __shared__ u16 ks[64][72];
  __shared__ u16 vs[64][72];
  __shared__ u16 ps[4][16][72];
  const int qt = blockIdx.x, h = blockIdx.y, b = blockIdx.z;
  const int t = threadIdx.x, wid = t >> 6, lane = t & 63, lg = lane >> 4, lm = lane & 15;
  const int q0 = qt * 64, qw = q0 + wid * 16;
  s16x8 qh[2];
#pragma unroll
  for (int s = 0; s < 2; ++s) {
    size_t off = ((size_t)(b*SLQ + qw + lm)) * DM + h*HD + s*32 + lg*8;
    qh[s] = *(const s16x8*)(qb + off);
  }
  f32x4 O[4];
#pragma unroll
  for (int j = 0; j < 4; ++j) O[j] = (f32x4)(0.0f);
  float m_r[4] = {-INFINITY, -INFINITY, -INFINITY, -INFINITY};
  float l_r[4] = {0.f, 0.f, 0.f, 0.f};   // per-lane partials (16 lanes/row)
  const int srow = t >> 2, sch = t & 3;
  for (int j0 = 0; j0 < SLK; j0 += 64) {
    {
      size_t koff = ((size_t)(b*SLK + j0 + srow)) * DM + h*HD + sch*16;
      *(s16x8*)&ks[srow][sch*16]     = *(const s16x8*)(kb + koff);
      *(s16x8*)&ks[srow][sch*16 + 8] = *(const s16x8*)(kb + koff + 8);
      size_t voff = (((size_t)b*NH + h)*HD + srow)*SLK + j0 + sch*16;
      *(s16x8*)&vs[srow][sch*16]     = *(const s16x8*)(vT + voff);
      *(s16x8*)&vs[srow][sch*16 + 8] = *(const s16x8*)(vT + voff + 8);
    }
    __syncthreads();
    // QK^T
    f32x4 sc[4];
#pragma unroll
    for (int j = 0; j < 4; ++j) {
      s16x8 kh0 = *(const s16x8*)&ks[j*16 + lm][lg*8];
      s16x8 kh1 = *(const s16x8*)&ks[j*16 + lm][32 + lg*8];
      f32x4 c = (f32x4)(0.0f);
      c = __builtin_amdgcn_mfma_f32_16x16x32_bf16(qh[0], kh0, c, 0, 0, 0);
      c = __builtin_amdgcn_mfma_f32_16x16x32_bf16(qh[1], kh1, c, 0, 0, 0);
      sc[j] = c;
    }
    // mask + deferred-max base-2 softmax per q-row (reg r)
#pragma unroll
    for (int r = 0; r < 4; ++r) {
      size_t mrow = ((size_t)(b*SLQ + qw + lg*4 + r)) * (SLK/32) + (j0 >> 5);
      u32 w0 = mbits[mrow], w1 = mbits[mrow + 1];
      float sv[4];
#pragma unroll
      for (int j = 0; j < 4; ++j) {
        u32 w = (j < 2) ? w0 : w1;
        int bit = (w >> ((j*16 + lm) & 31)) & 1;
        sv[j] = bit ? sc[j][r] * C2 : -1e9f;
      }
      float pmax = fmaxf(fmaxf(sv[0], sv[1]), fmaxf(sv[2], sv[3]));
      if (!__all(pmax <= m_r[r] + 8.0f)) {       // slow path: rare
        float mx = pmax;
#pragma unroll
        for (int off = 1; off < 16; off <<= 1) mx = fmaxf(mx, __shfl_xor(mx, off, 64));
        float mnew  = fmaxf(m_r[r], mx);
        float alpha = EXP2(m_r[r] - mnew);       // m=-inf -> 0
        m_r[r] = mnew;
        l_r[r] *= alpha;
#pragma unroll
        for (int j = 0; j < 4; ++j) O[j][r] *= alpha;
      }
      float p0 = EXP2(sv[0] - m_r[r]);
      float p1 = EXP2(sv[1] - m_r[r]);
      float p2 = EXP2(sv[2] - m_r[r]);
      float p3 = EXP2(sv[3] - m_r[r]);
      l_r[r] += (p0 + p1) + (p2 + p3);
      u32 pk01 = cvtpk(p0, p1);
      u32 pk23 = cvtpk(p2, p3);
      ps[wid][lg*4 + r][0*16 + lm] = (u16)(pk01 & 0xffffu);
      ps[wid][lg*4 + r][1*16 + lm] = (u16)(pk01 >> 16);
      ps[wid][lg*4 + r][2*16 + lm] = (u16)(pk23 & 0xffffu);
      ps[wid][lg*4 + r][3*16 + lm] = (u16)(pk23 >> 16);
    }
    // PV
    {
      s16x8 pa0 = *(const s16x8*)&ps[wid][lm][lg*8];
      s16x8 pa1 = *(const s16x8*)&ps[wid][lm][32 + lg*8];
#pragma unroll
      for (int j = 0; j < 4; ++j) {
        s16x8 vb0 = *(const s16x8*)&vs[j*16 + lm][lg*8];
        s16x8 vb1 = *(const s16x8*)&vs[j*16 + lm][32 + lg*8];
        O[j] = __builtin_amdgcn_mfma_f32_16x16x32_bf16(pa0, vb0, O[j], 0, 0, 0);
        O[j] = __builtin_amdgcn_mfma_f32_16x16x32_bf16(pa1, vb1, O[j], 0, 0, 0);
      }
    }
    __syncthreads();
  }
  // final l reduction across the 16 lanes of each row (once)
#pragma unroll
  for (int r = 0; r < 4; ++r) {
#pragma unroll
    for (int off = 1; off < 16; off <<= 1) l_r[r] += __shfl_xor(l_r[r], off, 64);
  }
#pragma unroll
  for (int j = 0; j < 4; ++j)
#pragma unroll
    for (int r = 0; r < 4; ++r) {
      float v = O[j][r] / l_r[r];
      size_t row = (size_t)(b*SLQ + qw + lg*4 + r);
      wv[row*DM + h*HD + j*16 + lm] = f2bf(v);
    }
  if (lm == 0) {
#pragma unroll
    for (int r = 0; r < 4; ++r) {
      float* mp = ml + ((size_t)(b*NH + h)*SLQ + qw + lg*4 + r) * 2;
      mp[0] = m_r[r]; mp[1] = l_r[r];   // m in base-2 units
    }
  }
}

// ---------------------------------------------------------------------------
// weight_mean: block = ONE (64q x 64k) tile; 2048 blocks; loop h in-block.
// Base-2: w = exp2(fma(c, C2, -m)) / l with attn's stored base-2 (m,l).
// ---------------------------------------------------------------------------
__global__ __launch_bounds__(256) void wmean_mfma_k(
    const u16* __restrict__ qb, const u16* __restrict__ kb,
    const u32* __restrict__ mbits, const float* __restrict__ ml,
    float* __restrict__ out1) {
  __shared__ u16 ks[64][72];
  const int t = threadIdx.x, wid = t >> 6, lane = t & 63, lg = lane >> 4, lm = lane & 15;
  const int j0 = blockIdx.x * 64, q0 = blockIdx.y * 64, b = blockIdx.z;
  const int qw = q0 + wid * 16;
  const int srow = t >> 2, sch = t & 3;
  f32x4 wm[4];
#pragma unroll
  for (int j = 0; j < 4; ++j) wm[j] = (f32x4)(0.0f);
  u32 w0[4], w1[4];
#pragma unroll
  for (int r = 0; r < 4; ++r) {
    size_t mrow = ((size_t)(b*SLQ + qw + lg*4 + r)) * (SLK/32) + (j0 >> 5);
    w0[r] = mbits[mrow]; w1[r] = mbits[mrow + 1];
  }
  for (int h = 0; h < NH; ++h) {
    __syncthreads();   // previous-h ks reads done
    {
      size_t koff = ((size_t)(b*SLK + j0 + srow)) * DM + h*HD + sch*16;
      *(s16x8*)&ks[srow][sch*16]     = *(const s16x8*)(kb + koff);
      *(s16x8*)&ks[srow][sch*16 + 8] = *(const s16x8*)(kb + koff + 8);
    }
    __syncthreads();
    s16x8 qh0, qh1;
    {
      size_t off = ((size_t)(b*SLQ + qw + lm)) * DM + h*HD + lg*8;
      qh0 = *(const s16x8*)(qb + off);
      qh1 = *(const s16x8*)(qb + off + 32);
    }
    float mr[4], li[4];
#pragma unroll
    for (int r = 0; r < 4; ++r) {
      const float* mp = ml + ((size_t)(b*NH + h)*SLQ + qw + lg*4 + r) * 2;
      mr[r] = mp[0]; li[r] = 1.0f / mp[1];
    }
#pragma unroll
    for (int j = 0; j < 4; ++j) {
      s16x8 kh0 = *(const s16x8*)&ks[j*16 + lm][lg*8];
      s16x8 kh1 = *(const s16x8*)&ks[j*16 + lm][32 + lg*8];
      f32x4 c = (f32x4)(0.0f);
      c = __builtin_amdgcn_mfma_f32_16x16x32_bf16(qh0, kh0, c, 0, 0, 0);
      c = __builtin_amdgcn_mfma_f32_16x16x32_bf16(qh1, kh1, c, 0, 0, 0);
#pragma unroll
      for (int r = 0; r < 4; ++r) {
        u32 w = (j < 2) ? w0[r] : w1[r];
        int bit = (w >> ((j*16 + lm) & 31)) & 1;
        float wvv = bit ? EXP2(__builtin_fmaf(c[r], C2, -mr[r])) * li[r] : 0.f;
        wm[j][r] += wvv;
      }
    }
  }
#pragma unroll
  for (int j = 0; j < 4; ++j)
#pragma unroll
    for (int r = 0; r < 4; ++r)
      out1[((size_t)b*SLQ + qw + lg*4 + r) * SLK + j0 + j*16 + lm]
          = wm[j][r] * (1.0f / NH);
}

// ---------------------------------------------------------------------------
extern "C" void kernel_launch(void* const* d_in, const int* in_sizes, int n_in,
                              void* d_out, int out_size, void* d_ws, size_t ws_size,
                              hipStream_t stream) {
  const float* mq    = (const float*)d_in[0];
  const float* reply = (const float*)d_in[1];
  const int*   maskp = (const int*)  d_in[2];
  const float* Wq = (const float*)d_in[3];
  const float* bq = (const float*)d_in[4];
  const float* Wk = (const float*)d_in[5];
  const float* bk = (const float*)d_in[6];
  const float* Wv = (const float*)d_in[7];
  const float* bv = (const float*)d_in[8];
  const float* Wo = (const float*)d_in[9];
  const float* bo = (const float*)d_in[10];

  float* out0 = (float*)d_out;
  float* out1 = out0 + (size_t)NB*SLQ*DM;

  // workspace carve -- total ~82 MB
  char* w = (char*)d_ws;
  auto carve = [&](size_t bytes) { char* p = w; w += bytes; return p; };
  u16* WqT = (u16*)carve((size_t)DM*DM*2);
  u16* WkT = (u16*)carve((size_t)DM*DM*2);
  u16* WvT = (u16*)carve((size_t)DM*DM*2);
  u16* WoT = (u16*)carve((size_t)DM*DM*2);
  u16* mqb = (u16*)carve((size_t)NB*SLQ*DM*2);
  u16* rpb = (u16*)carve((size_t)NB*SLK*DM*2);
  u16* qbf = (u16*)carve((size_t)NB*SLQ*DM*2);
  u16* kbf = (u16*)carve((size_t)NB*SLK*DM*2);
  u16* vT  = (u16*)carve((size_t)NB*SLK*DM*2);
  u16* wvb = (u16*)carve((size_t)NB*SLQ*DM*2);
  float* mlb = (float*)carve((size_t)NB*NH*SLQ*2*4);
  unsigned long long* mbits = (unsigned long long*)carve((size_t)NB*SLQ*SLK/8);

  cvt2_bf16_k<<<768, 256, 0, stream>>>(mq, mqb, NB*SLQ*DM, reply, rpb, NB*SLK*DM);
  maskbits_k<<<256, 256, 0, stream>>>(maskp, mbits, NB*SLQ*SLK/64);
  convT4_k<<<dim3(16, 16, 4), 256, 0, stream>>>(
      Wq, Wk, Wv, Wo, WqT, WkT, WvT, WoT);

  // grouped q/k/v projections: one 1280-block launch
  proj_gemm_k<<<1280, 256, 0, stream>>>(
      mqb, rpb, WqT, WkT, WvT, bq, bk, bv, qbf, kbf, vT);

  attn_mfma_k<<<dim3(SLQ/64, NH, NB), 256, 0, stream>>>(
      qbf, kbf, vT, (const u32*)mbits, wvb, mlb);

  wmean_mfma_k<<<dim3(SLK/64, SLQ/64, NB), 256, 0, stream>>>(
      qbf, kbf, (const u32*)mbits, mlb, out1);

  gemm_o_k<<<dim3(DM/128, (NB*SLQ)/128), 256, 0, stream>>>(wvb, WoT, bo, out0);
}

// Round 12
// 293.783 us; speedup vs baseline: 1.2198x; 1.0453x over previous
//
#include <hip/hip_runtime.h>
#include <math.h>

#define NB   4
#define NH   16
#define SLQ  1024
#define SLK  2048
#define DM   1024
#define HD   64

typedef __attribute__((ext_vector_type(8))) short s16x8;
typedef __attribute__((ext_vector_type(4))) short s16x4;
typedef __attribute__((ext_vector_type(4))) float f32x4;
typedef unsigned short u16;
typedef unsigned int   u32;

#if defined(__has_builtin)
#if __has_builtin(__builtin_amdgcn_exp2f)
#define EXP2(x) __builtin_amdgcn_exp2f(x)
#else
#define EXP2(x) exp2f(x)
#endif
#else
#define EXP2(x) exp2f(x)
#endif

// 0.125 * log2(e): scores scaled to base-2 inside attn/wmean
#define C2 0.18033688011116012f

__device__ inline u16 f2bf(float f) {
  u32 u = __float_as_uint(f);
  u32 r = u + 0x7fffu + ((u >> 16) & 1u);
  return (u16)(r >> 16);
}
__device__ inline float bf2f(u16 h) { return __uint_as_float(((u32)h) << 16); }

// pack 2 f32 -> 2 bf16 (RNE), lo = a, hi = b
__device__ __forceinline__ u32 cvtpk(float a, float b) {
  u32 r;
  asm("v_cvt_pk_bf16_f32 %0, %1, %2" : "=v"(r) : "v"(a), "v"(b));
  return r;
}

// async global->LDS, 16B per lane; LDS dest must be wave-uniform base.
__device__ __forceinline__ void gl16(const void* g, void* l) {
  __builtin_amdgcn_global_load_lds(
      (const __attribute__((address_space(1))) unsigned int*)g,
      (__attribute__((address_space(3))) unsigned int*)l, 16, 0, 0);
}

// ---------------------------------------------------------------------------
// prep_k: fused setup, one launch, 2048 blocks by range:
//   [0,256)     mask -> bitmask (ballot, grid-stride)
//   [256,1024)  f32 -> bf16 for mq and reply (768 blocks, grid-stride)
//   [1024,2048) 4x W[1024][1024] -> WT[n][k] bf16 (tile per block)
// ---------------------------------------------------------------------------
__global__ __launch_bounds__(256) void prep_k(
    const int* __restrict__ mask, unsigned long long* __restrict__ bits,
    const float* __restrict__ mq, u16* __restrict__ mqb,
    const float* __restrict__ reply, u16* __restrict__ rpb,
    const float* __restrict__ W0, const float* __restrict__ W1,
    const float* __restrict__ W2, const float* __restrict__ W3,
    u16* __restrict__ T0, u16* __restrict__ T1,
    u16* __restrict__ T2, u16* __restrict__ T3) {
  __shared__ float ts[64][68];
  const int gid = blockIdx.x, t = threadIdx.x;
  if (gid < 256) {
    const int nwords = NB*SLQ*SLK/64;
    int gw   = (gid * 256 + t) >> 6;
    int lane = t & 63;
    const int nw = (256 * 256) >> 6;   // 1024 waves
    for (int w = gw; w < nwords; w += nw) {
      int m = mask[(size_t)w * 64 + lane];
      unsigned long long b = __ballot(m != 0);
      if (lane == 0) bits[w] = b;
    }
  } else if (gid < 1024) {
    const int g = gid - 256;
    const int na = NB*SLQ*DM, nb = NB*SLK*DM;
    const int stride = 768 * 256 * 8;
    for (int i = (g * 256 + t) * 8; i < na + nb; i += stride) {
      const float* s; u16* d; int off;
      if (i < na) { s = mq; d = mqb; off = i; } else { s = reply; d = rpb; off = i - na; }
      float4 x = *(const float4*)(s + off);
      float4 y = *(const float4*)(s + off + 4);
      s16x8 o;
      o[0] = (short)f2bf(x.x); o[1] = (short)f2bf(x.y);
      o[2] = (short)f2bf(x.z); o[3] = (short)f2bf(x.w);
      o[4] = (short)f2bf(y.x); o[5] = (short)f2bf(y.y);
      o[6] = (short)f2bf(y.z); o[7] = (short)f2bf(y.w);
      *(s16x8*)(d + off) = o;
    }
  } else {
    const int g = gid - 1024;
    const int cx = g & 15, ry = (g >> 4) & 15, wz = g >> 8;
    const float* W; u16* T;
    switch (wz) {
      case 0:  W = W0; T = T0; break;
      case 1:  W = W1; T = T1; break;
      case 2:  W = W2; T = T2; break;
      default: W = W3; T = T3; break;
    }
    const int r0 = ry * 64, c0 = cx * 64;
    const int rr = t >> 4, cc = t & 15;
#pragma unroll
    for (int p = 0; p < 4; ++p) {
      float4 v = *(const float4*)(W + (size_t)(r0 + rr + p*16) * DM + c0 + cc*4);
      *(float4*)&ts[rr + p*16][cc*4] = v;
    }
    __syncthreads();
    const int c = t >> 2, ch = t & 3;
    s16x8 h0, h1;
#pragma unroll
    for (int i = 0; i < 8; ++i) {
      h0[i] = (short)f2bf(ts[ch*16 + i][c]);
      h1[i] = (short)f2bf(ts[ch*16 + 8 + i][c]);
    }
    size_t base = (size_t)(c0 + c) * DM + r0 + ch*16;
    *(s16x8*)(T + base) = h0; *(s16x8*)(T + base + 8) = h1;
  }
}

// ---------------------------------------------------------------------------
// Grouped projection GEMM (unchanged from r10): q (natural), k (natural),
// v (transposed vT). 1280 blocks; k/v interleaved pairs share A-tiles.
// ---------------------------------------------------------------------------
__global__ __launch_bounds__(256) void proj_gemm_k(
    const u16* __restrict__ mqb, const u16* __restrict__ rpb,
    const u16* __restrict__ WqT, const u16* __restrict__ WkT,
    const u16* __restrict__ WvT,
    const float* __restrict__ bq, const float* __restrict__ bk,
    const float* __restrict__ bv,
    u16* __restrict__ qbf, u16* __restrict__ kbf, u16* __restrict__ vTp) {
  const int gid = blockIdx.x;
  const u16* A; const u16* BT; const float* bias; u16* out;
  int mode, mt, nt;
  if (gid < 256) {
    A = mqb; BT = WqT; bias = bq; out = qbf; mode = 0;
    nt = gid & 7; mt = gid >> 3;
  } else {
    const int g = gid - 256, pair = g >> 1;
    nt = pair & 7; mt = pair >> 3;
    if ((g & 1) == 0) { A = rpb; BT = WkT; bias = bk; out = kbf; mode = 0; }
    else              { A = rpb; BT = WvT; bias = bv; out = vTp; mode = 1; }
  }
  const int m0 = mt * 128, n0 = nt * 128;

  __shared__ u16 Ah[128 * 32];
  __shared__ u16 Bh[128 * 32];
  const int t = threadIdx.x;
  const int wid = t >> 6, lane = t & 63, lg = lane >> 4, lm = lane & 15;
  const int wr = wid >> 1, wc = wid & 1;
  f32x4 acc[4][4];
#pragma unroll
  for (int i = 0; i < 4; ++i)
#pragma unroll
    for (int j = 0; j < 4; ++j) acc[i][j] = (f32x4)(0.0f);

  const int c0 = wid * 2, c1 = wid * 2 + 1;
  const int sr0 = c0 * 16 + (lane >> 2), sr1 = c1 * 16 + (lane >> 2);
  const int spc = (lane & 3) * 8;
  for (int k0 = 0; k0 < DM; k0 += 32) {
    gl16(A  + (size_t)(m0 + sr0) * DM + k0 + spc, &Ah[c0 * 512]);
    gl16(A  + (size_t)(m0 + sr1) * DM + k0 + spc, &Ah[c1 * 512]);
    gl16(BT + (size_t)(n0 + sr0) * DM + k0 + spc, &Bh[c0 * 512]);
    gl16(BT + (size_t)(n0 + sr1) * DM + k0 + spc, &Bh[c1 * 512]);
    __syncthreads();
    s16x8 ah[4], bh[4];
#pragma unroll
    for (int i = 0; i < 4; ++i) {
      ah[i] = *(const s16x8*)&Ah[(wr*64 + i*16 + lm) * 32 + lg*8];
      bh[i] = *(const s16x8*)&Bh[(wc*64 + i*16 + lm) * 32 + lg*8];
    }
#pragma unroll
    for (int i = 0; i < 4; ++i)
#pragma unroll
      for (int j = 0; j < 4; ++j)
        acc[i][j] = __builtin_amdgcn_mfma_f32_16x16x32_bf16(ah[i], bh[j], acc[i][j], 0, 0, 0);
    __syncthreads();
  }
#pragma unroll
  for (int i = 0; i < 4; ++i)
#pragma unroll
    for (int j = 0; j < 4; ++j) {
      const int colg = n0 + wc*64 + j*16 + lm;
      const int rowb = m0 + wr*64 + i*16 + lg*4;
      const float bcol = bias[colg];
      if (mode == 0) {
#pragma unroll
        for (int r = 0; r < 4; ++r)
          out[(size_t)(rowb + r) * DM + colg] = f2bf(acc[i][j][r] + bcol);
      } else {  // vT transposed bf16
        const int bb = rowb >> 11, key = rowb & 2047;
        const int hh = colg >> 6, dv = colg & 63;
        s16x4 pk;
#pragma unroll
        for (int r = 0; r < 4; ++r) pk[r] = (short)f2bf(acc[i][j][r] + bcol);
        *(s16x4*)(out + (((size_t)bb*NH + hh)*HD + dv)*SLK + key) = pk;
      }
    }
}

// ---------------------------------------------------------------------------
// Flash attention (unchanged from r11; 101us, VGPR 64). Base-2 softmax,
// deferred-max, cvt_pk P-store, per-lane l partials.
// ---------------------------------------------------------------------------
__global__ __launch_bounds__(256) void attn_mfma_k(
    const u16* __restrict__ qb, const u16* __restrict__ kb,
    const u16* __restrict__ vT, const u32* __restrict__ mbits,
    u16* __restrict__ wv, float* __restrict__ ml) {
  __shared__ u16 ks[64][72];
  __shared__ u16 vs[64][72];
  __shared__ u16 ps[4][16][72];
  const int qt = blockIdx.x, h = blockIdx.y, b = blockIdx.z;
  const int t = threadIdx.x, wid = t >> 6, lane = t & 63, lg = lane >> 4, lm = lane & 15;
  const int q0 = qt * 64, qw = q0 + wid * 16;
  s16x8 qh[2];
#pragma unroll
  for (int s = 0; s < 2; ++s) {
    size_t off = ((size_t)(b*SLQ + qw + lm)) * DM + h*HD + s*32 + lg*8;
    qh[s] = *(const s16x8*)(qb + off);
  }
  f32x4 O[4];
#pragma unroll
  for (int j = 0; j < 4; ++j) O[j] = (f32x4)(0.0f);
  float m_r[4] = {-INFINITY, -INFINITY, -INFINITY, -INFINITY};
  float l_r[4] = {0.f, 0.f, 0.f, 0.f};   // per-lane partials (16 lanes/row)
  const int srow = t >> 2, sch = t & 3;
  for (int j0 = 0; j0 < SLK; j0 += 64) {
    {
      size_t koff = ((size_t)(b*SLK + j0 + srow)) * DM + h*HD + sch*16;
      *(s16x8*)&ks[srow][sch*16]     = *(const s16x8*)(kb + koff);
      *(s16x8*)&ks[srow][sch*16 + 8] = *(const s16x8*)(kb + koff + 8);
      size_t voff = (((size_t)b*NH + h)*HD + srow)*SLK + j0 + sch*16;
      *(s16x8*)&vs[srow][sch*16]     = *(const s16x8*)(vT + voff);
      *(s16x8*)&vs[srow][sch*16 + 8] = *(const s16x8*)(vT + voff + 8);
    }
    __syncthreads();
    // QK^T
    f32x4 sc[4];
#pragma unroll
    for (int j = 0; j < 4; ++j) {
      s16x8 kh0 = *(const s16x8*)&ks[j*16 + lm][lg*8];
      s16x8 kh1 = *(const s16x8*)&ks[j*16 + lm][32 + lg*8];
      f32x4 c = (f32x4)(0.0f);
      c = __builtin_amdgcn_mfma_f32_16x16x32_bf16(qh[0], kh0, c, 0, 0, 0);
      c = __builtin_amdgcn_mfma_f32_16x16x32_bf16(qh[1], kh1, c, 0, 0, 0);
      sc[j] = c;
    }
    // mask + deferred-max base-2 softmax per q-row (reg r)
#pragma unroll
    for (int r = 0; r < 4; ++r) {
      size_t mrow = ((size_t)(b*SLQ + qw + lg*4 + r)) * (SLK/32) + (j0 >> 5);
      u32 w0 = mbits[mrow], w1 = mbits[mrow + 1];
      float sv[4];
#pragma unroll
      for (int j = 0; j < 4; ++j) {
        u32 w = (j < 2) ? w0 : w1;
        int bit = (w >> ((j*16 + lm) & 31)) & 1;
        sv[j] = bit ? sc[j][r] * C2 : -1e9f;
      }
      float pmax = fmaxf(fmaxf(sv[0], sv[1]), fmaxf(sv[2], sv[3]));
      if (!__all(pmax <= m_r[r] + 8.0f)) {       // slow path: rare
        float mx = pmax;
#pragma unroll
        for (int off = 1; off < 16; off <<= 1) mx = fmaxf(mx, __shfl_xor(mx, off, 64));
        float mnew  = fmaxf(m_r[r], mx);
        float alpha = EXP2(m_r[r] - mnew);       // m=-inf -> 0
        m_r[r] = mnew;
        l_r[r] *= alpha;
#pragma unroll
        for (int j = 0; j < 4; ++j) O[j][r] *= alpha;
      }
      float p0 = EXP2(sv[0] - m_r[r]);
      float p1 = EXP2(sv[1] - m_r[r]);
      float p2 = EXP2(sv[2] - m_r[r]);
      float p3 = EXP2(sv[3] - m_r[r]);
      l_r[r] += (p0 + p1) + (p2 + p3);
      u32 pk01 = cvtpk(p0, p1);
      u32 pk23 = cvtpk(p2, p3);
      ps[wid][lg*4 + r][0*16 + lm] = (u16)(pk01 & 0xffffu);
      ps[wid][lg*4 + r][1*16 + lm] = (u16)(pk01 >> 16);
      ps[wid][lg*4 + r][2*16 + lm] = (u16)(pk23 & 0xffffu);
      ps[wid][lg*4 + r][3*16 + lm] = (u16)(pk23 >> 16);
    }
    // PV
    {
      s16x8 pa0 = *(const s16x8*)&ps[wid][lm][lg*8];
      s16x8 pa1 = *(const s16x8*)&ps[wid][lm][32 + lg*8];
#pragma unroll
      for (int j = 0; j < 4; ++j) {
        s16x8 vb0 = *(const s16x8*)&vs[j*16 + lm][lg*8];
        s16x8 vb1 = *(const s16x8*)&vs[j*16 + lm][32 + lg*8];
        O[j] = __builtin_amdgcn_mfma_f32_16x16x32_bf16(pa0, vb0, O[j], 0, 0, 0);
        O[j] = __builtin_amdgcn_mfma_f32_16x16x32_bf16(pa1, vb1, O[j], 0, 0, 0);
      }
    }
    __syncthreads();
  }
  // final l reduction across the 16 lanes of each row (once)
#pragma unroll
  for (int r = 0; r < 4; ++r) {
#pragma unroll
    for (int off = 1; off < 16; off <<= 1) l_r[r] += __shfl_xor(l_r[r], off, 64);
  }
#pragma unroll
  for (int j = 0; j < 4; ++j)
#pragma unroll
    for (int r = 0; r < 4; ++r) {
      float v = O[j][r] / l_r[r];
      size_t row = (size_t)(b*SLQ + qw + lg*4 + r);
      wv[row*DM + h*HD + j*16 + lm] = f2bf(v);
    }
  if (lm == 0) {
#pragma unroll
    for (int r = 0; r < 4; ++r) {
      float* mp = ml + ((size_t)(b*NH + h)*SLQ + qw + lg*4 + r) * 2;
      mp[0] = m_r[r]; mp[1] = l_r[r];   // m in base-2 units
    }
  }
}

// ---------------------------------------------------------------------------
// tail_k: fused wmean + output projection, one launch, 2304 blocks:
//   [0,256)     gemm_o: out0 = wvb@WoT + bo (f32)   -- dispatched first so
//               its 256 blocks (1/CU solo) hide under wmean's 2048.
//   [256,2304)  wmean: one 64q x 64k tile each, loop 16 heads in-block.
// LDS overlaid in one 16 KB buffer.
// ---------------------------------------------------------------------------
__global__ __launch_bounds__(256) void tail_k(
    const u16* __restrict__ qb, const u16* __restrict__ kb,
    const u32* __restrict__ mbits, const float* __restrict__ ml,
    float* __restrict__ out1,
    const u16* __restrict__ wvb, const u16* __restrict__ WoT,
    const float* __restrict__ bo, float* __restrict__ out0) {
  __shared__ u16 lds[128 * 32 * 2];   // 16 KB
  const int gid = blockIdx.x, t = threadIdx.x;
  const int wid = t >> 6, lane = t & 63, lg = lane >> 4, lm = lane & 15;

  if (gid < 256) {
    // ---- output projection ----
    u16* Ah = lds;
    u16* Bh = lds + 128 * 32;
    const int m0 = (gid >> 3) * 128, n0 = (gid & 7) * 128;
    const int wr = wid >> 1, wc = wid & 1;
    f32x4 acc[4][4];
#pragma unroll
    for (int i = 0; i < 4; ++i)
#pragma unroll
      for (int j = 0; j < 4; ++j) acc[i][j] = (f32x4)(0.0f);
    const int c0 = wid * 2, c1 = wid * 2 + 1;
    const int sr0 = c0 * 16 + (lane >> 2), sr1 = c1 * 16 + (lane >> 2);
    const int spc = (lane & 3) * 8;
    for (int k0 = 0; k0 < DM; k0 += 32) {
      gl16(wvb + (size_t)(m0 + sr0) * DM + k0 + spc, &Ah[c0 * 512]);
      gl16(wvb + (size_t)(m0 + sr1) * DM + k0 + spc, &Ah[c1 * 512]);
      gl16(WoT + (size_t)(n0 + sr0) * DM + k0 + spc, &Bh[c0 * 512]);
      gl16(WoT + (size_t)(n0 + sr1) * DM + k0 + spc, &Bh[c1 * 512]);
      __syncthreads();
      s16x8 ah[4], bh[4];
#pragma unroll
      for (int i = 0; i < 4; ++i) {
        ah[i] = *(const s16x8*)&Ah[(wr*64 + i*16 + lm) * 32 + lg*8];
        bh[i] = *(const s16x8*)&Bh[(wc*64 + i*16 + lm) * 32 + lg*8];
      }
#pragma unroll
      for (int i = 0; i < 4; ++i)
#pragma unroll
        for (int j = 0; j < 4; ++j)
          acc[i][j] = __builtin_amdgcn_mfma_f32_16x16x32_bf16(ah[i], bh[j], acc[i][j], 0, 0, 0);
      __syncthreads();
    }
#pragma unroll
    for (int i = 0; i < 4; ++i)
#pragma unroll
      for (int j = 0; j < 4; ++j) {
        const int colg = n0 + wc*64 + j*16 + lm;
        const int rowb = m0 + wr*64 + i*16 + lg*4;
        const float bcol = bo[colg];
#pragma unroll
        for (int r = 0; r < 4; ++r)
          out0[(size_t)(rowb + r) * DM + colg] = acc[i][j][r] + bcol;
      }
  } else {
    // ---- weight_mean tile ----
    u16 (*ks)[72] = (u16(*)[72])lds;
    const int g = gid - 256;
    const int j0 = (g & 31) * 64, q0 = ((g >> 5) & 15) * 64, b = g >> 9;
    const int qw = q0 + wid * 16;
    const int srow = t >> 2, sch = t & 3;
    f32x4 wm[4];
#pragma unroll
    for (int j = 0; j < 4; ++j) wm[j] = (f32x4)(0.0f);
    u32 w0[4], w1[4];
#pragma unroll
    for (int r = 0; r < 4; ++r) {
      size_t mrow = ((size_t)(b*SLQ + qw + lg*4 + r)) * (SLK/32) + (j0 >> 5);
      w0[r] = mbits[mrow]; w1[r] = mbits[mrow + 1];
    }
    for (int h = 0; h < NH; ++h) {
      __syncthreads();   // previous-h ks reads done
      {
        size_t koff = ((size_t)(b*SLK + j0 + srow)) * DM + h*HD + sch*16;
        *(s16x8*)&ks[srow][sch*16]     = *(const s16x8*)(kb + koff);
        *(s16x8*)&ks[srow][sch*16 + 8] = *(const s16x8*)(kb + koff + 8);
      }
      __syncthreads();
      s16x8 qh0, qh1;
      {
        size_t off = ((size_t)(b*SLQ + qw + lm)) * DM + h*HD + lg*8;
        qh0 = *(const s16x8*)(qb + off);
        qh1 = *(const s16x8*)(qb + off + 32);
      }
      float mr[4], li[4];
#pragma unroll
      for (int r = 0; r < 4; ++r) {
        const float* mp = ml + ((size_t)(b*NH + h)*SLQ + qw + lg*4 + r) * 2;
        mr[r] = mp[0]; li[r] = 1.0f / mp[1];
      }
#pragma unroll
      for (int j = 0; j < 4; ++j) {
        s16x8 kh0 = *(const s16x8*)&ks[j*16 + lm][lg*8];
        s16x8 kh1 = *(const s16x8*)&ks[j*16 + lm][32 + lg*8];
        f32x4 c = (f32x4)(0.0f);
        c = __builtin_amdgcn_mfma_f32_16x16x32_bf16(qh0, kh0, c, 0, 0, 0);
        c = __builtin_amdgcn_mfma_f32_16x16x32_bf16(qh1, kh1, c, 0, 0, 0);
#pragma unroll
        for (int r = 0; r < 4; ++r) {
          u32 w = (j < 2) ? w0[r] : w1[r];
          int bit = (w >> ((j*16 + lm) & 31)) & 1;
          float wvv = bit ? EXP2(__builtin_fmaf(c[r], C2, -mr[r])) * li[r] : 0.f;
          wm[j][r] += wvv;
        }
      }
    }
#pragma unroll
    for (int j = 0; j < 4; ++j)
#pragma unroll
      for (int r = 0; r < 4; ++r)
        out1[((size_t)b*SLQ + qw + lg*4 + r) * SLK + j0 + j*16 + lm]
            = wm[j][r] * (1.0f / NH);
  }
}

// ---------------------------------------------------------------------------
extern "C" void kernel_launch(void* const* d_in, const int* in_sizes, int n_in,
                              void* d_out, int out_size, void* d_ws, size_t ws_size,
                              hipStream_t stream) {
  const float* mq    = (const float*)d_in[0];
  const float* reply = (const float*)d_in[1];
  const int*   maskp = (const int*)  d_in[2];
  const float* Wq = (const float*)d_in[3];
  const float* bq = (const float*)d_in[4];
  const float* Wk = (const float*)d_in[5];
  const float* bk = (const float*)d_in[6];
  const float* Wv = (const float*)d_in[7];
  const float* bv = (const float*)d_in[8];
  const float* Wo = (const float*)d_in[9];
  const float* bo = (const float*)d_in[10];

  float* out0 = (float*)d_out;
  float* out1 = out0 + (size_t)NB*SLQ*DM;

  // workspace carve -- total ~82 MB
  char* w = (char*)d_ws;
  auto carve = [&](size_t bytes) { char* p = w; w += bytes; return p; };
  u16* WqT = (u16*)carve((size_t)DM*DM*2);
  u16* WkT = (u16*)carve((size_t)DM*DM*2);
  u16* WvT = (u16*)carve((size_t)DM*DM*2);
  u16* WoT = (u16*)carve((size_t)DM*DM*2);
  u16* mqb = (u16*)carve((size_t)NB*SLQ*DM*2);
  u16* rpb = (u16*)carve((size_t)NB*SLK*DM*2);
  u16* qbf = (u16*)carve((size_t)NB*SLQ*DM*2);
  u16* kbf = (u16*)carve((size_t)NB*SLK*DM*2);
  u16* vT  = (u16*)carve((size_t)NB*SLK*DM*2);
  u16* wvb = (u16*)carve((size_t)NB*SLQ*DM*2);
  float* mlb = (float*)carve((size_t)NB*NH*SLQ*2*4);
  unsigned long long* mbits = (unsigned long long*)carve((size_t)NB*SLQ*SLK/8);

  // fused setup: maskbits + cvt(x2) + convT(x4) in one launch
  prep_k<<<2048, 256, 0, stream>>>(
      maskp, mbits, mq, mqb, reply, rpb,
      Wq, Wk, Wv, Wo, WqT, WkT, WvT, WoT);

  // grouped q/k/v projections
  proj_gemm_k<<<1280, 256, 0, stream>>>(
      mqb, rpb, WqT, WkT, WvT, bq, bk, bv, qbf, kbf, vT);

  attn_mfma_k<<<dim3(SLQ/64, NH, NB), 256, 0, stream>>>(
      qbf, kbf, vT, (const u32*)mbits, wvb, mlb);

  // fused tail: output projection (256 blocks, first) + weight_mean (2048)
  tail_k<<<2304, 256, 0, stream>>>(
      qbf, kbf, (const u32*)mbits, mlb, out1, wvb, WoT, bo, out0);
}